// Round 11
// baseline (391.916 us; speedup 1.0000x reference)
//
#include <hip/hip_runtime.h>

#define N_NODES 50000
#define E_EDGES 800000
#define E_TOT   (E_EDGES + N_NODES)   // edges + self loops
#define P_PAIRS 200000
#define IN_DIM  32
#define HID     64
#define HEADS   4
#define D       256
#define NEG_SLOPE 0.2f
#define SCAN_BS 1024
#define LOG2E 1.4426950408889634f

typedef short    s16x8 __attribute__((ext_vector_type(8)));
typedef float    f32x4 __attribute__((ext_vector_type(4)));
typedef _Float16 f16x8 __attribute__((ext_vector_type(8)));

__device__ __forceinline__ float ex2(float v) { return __builtin_amdgcn_exp2f(v); }

__device__ __forceinline__ unsigned short bf16_rne(float f) {
  unsigned u = __float_as_uint(f);
  u += 0x7FFFu + ((u >> 16) & 1u);
  return (unsigned short)(u >> 16);
}
__device__ __forceinline__ float bf16f(unsigned short h) {
  return __uint_as_float(((unsigned)h) << 16);
}

__device__ __forceinline__ void edge_sd(const int* __restrict__ ei, int e, int& s, int& d) {
  if (e < E_EDGES) { s = ei[e]; d = ei[E_EDGES + e]; }
  else             { s = d = e - E_EDGES; }
}

// ================= CSR build (dst-grouped) =================
__global__ void count_k(const int* __restrict__ ei, int* __restrict__ deg) {
  int e = blockIdx.x * 256 + threadIdx.x;
  if (e >= E_TOT) return;
  int s, d; edge_sd(ei, e, s, d);
  atomicAdd(&deg[d], 1);
}

__global__ __launch_bounds__(SCAN_BS) void scan_block_k(const int* __restrict__ in,
                                                        int* __restrict__ out,
                                                        int* __restrict__ bsum, int n) {
  __shared__ int tmp[SCAN_BS];
  int g = blockIdx.x * SCAN_BS + threadIdx.x;
  tmp[threadIdx.x] = (g < n) ? in[g] : 0;
  __syncthreads();
  for (int off = 1; off < SCAN_BS; off <<= 1) {
    int t = 0;
    if ((int)threadIdx.x >= off) t = tmp[threadIdx.x - off];
    __syncthreads();
    if ((int)threadIdx.x >= off) tmp[threadIdx.x] += t;
    __syncthreads();
  }
  if (g < n) out[g] = tmp[threadIdx.x];
  if (threadIdx.x == SCAN_BS - 1) bsum[blockIdx.x] = tmp[SCAN_BS - 1];
}

__global__ void scan_top_k(int* __restrict__ bsum, int nb) {
  __shared__ int tmp[256];
  tmp[threadIdx.x] = ((int)threadIdx.x < nb) ? bsum[threadIdx.x] : 0;
  __syncthreads();
  for (int off = 1; off < 256; off <<= 1) {
    int t = 0;
    if ((int)threadIdx.x >= off) t = tmp[threadIdx.x - off];
    __syncthreads();
    if ((int)threadIdx.x >= off) tmp[threadIdx.x] += t;
    __syncthreads();
  }
  if ((int)threadIdx.x < nb) bsum[threadIdx.x] = tmp[threadIdx.x];
}

__global__ void add_off_k(const int* __restrict__ scan_out,
                          const int* __restrict__ bsum,
                          int* __restrict__ rowptr) {
  int g = blockIdx.x * 256 + threadIdx.x;
  if (g >= N_NODES) return;
  int blk = g / SCAN_BS;
  int add = blk ? bsum[blk - 1] : 0;
  rowptr[g + 1] = scan_out[g] + add;
  if (g == 0) rowptr[0] = 0;
}

__global__ void scatter_k(const int* __restrict__ ei,
                          const int* __restrict__ rowptr,
                          int* __restrict__ pos, int* __restrict__ csr) {
  int e = blockIdx.x * 256 + threadIdx.x;
  if (e >= E_TOT) return;
  int s, d; edge_sd(ei, e, s, d);
  int idx = rowptr[d] + atomicAdd(&pos[d], 1);
  csr[idx] = s;
}

// ================ layer-1 algebraic restructure ================
__global__ void prep_wa1_k(const float* __restrict__ W1,
                           const float* __restrict__ as1,
                           const float* __restrict__ ad1,
                           float* __restrict__ wa_s, float* __restrict__ wa_d) {
  int t = threadIdx.x;                  // one block of 256
  int kk = (t >> 2) & 31, h = t & 3;
  const float* att = (t < 128) ? as1 : ad1;
  float sum = 0.f;
  for (int c = 0; c < HID; ++c) sum += W1[kk * D + h * HID + c] * att[h * HID + c];
  float* dst = (t < 128) ? wa_s : wa_d;
  dst[kk * 4 + h] = sum * LOG2E;
}

// W2T split: Whi/Wlo[col][k] = bf16 split of W2[k][col]
__global__ void prep_w2t_k(const float* __restrict__ W2,
                           unsigned short* __restrict__ Whi,
                           unsigned short* __restrict__ Wlo) {
  int g = blockIdx.x * 256 + threadIdx.x;   // 65536
  int col = g >> 8, k = g & 255;
  float w = W2[(size_t)k * D + col];
  unsigned short hi = bf16_rne(w);
  unsigned short lo = bf16_rne(w - bf16f(hi));
  Whi[g] = hi;  Wlo[g] = lo;                // [col][k] flat
}

// alps1[n,h] = x[n] . wa_s[:,h] ; 8 lanes per node, 8 nodes per wave
__global__ __launch_bounds__(256) void alphas1_k(const float* __restrict__ x,
                                                 const float* __restrict__ wa_s,
                                                 const float* __restrict__ wa_d,
                                                 float* __restrict__ alps,
                                                 float* __restrict__ alpd) {
  int w = (blockIdx.x * 256 + threadIdx.x) >> 6;
  int lane = threadIdx.x & 63;
  int n = w * 8 + (lane >> 3);
  int j = lane & 7;
  float4 xv = make_float4(0.f, 0.f, 0.f, 0.f);
  if (n < N_NODES) xv = *(const float4*)(x + (size_t)n * IN_DIM + j * 4);
  float ps[4] = {0.f, 0.f, 0.f, 0.f}, pd[4] = {0.f, 0.f, 0.f, 0.f};
  #pragma unroll
  for (int kk = 0; kk < 4; ++kk) {
    float xk = ((const float*)&xv)[kk];
    float4 ws = *(const float4*)(wa_s + (j * 4 + kk) * 4);
    float4 wd = *(const float4*)(wa_d + (j * 4 + kk) * 4);
    ps[0] += xk * ws.x; ps[1] += xk * ws.y; ps[2] += xk * ws.z; ps[3] += xk * ws.w;
    pd[0] += xk * wd.x; pd[1] += xk * wd.y; pd[2] += xk * wd.z; pd[3] += xk * wd.w;
  }
  #pragma unroll
  for (int off = 1; off < 8; off <<= 1) {
    #pragma unroll
    for (int h = 0; h < 4; ++h) {
      ps[h] += __shfl_xor(ps[h], off);
      pd[h] += __shfl_xor(pd[h], off);
    }
  }
  if (j == 0 && n < N_NODES) {
    *(float4*)(alps + n * 4) = make_float4(ps[0], ps[1], ps[2], ps[3]);
    *(float4*)(alpd + n * 4) = make_float4(pd[0], pd[1], pd[2], pd[3]);
  }
}

// x-space gather: agg[n][h][k<32] = (sum_e exp2 w * x[src][k]) / den[h]
__global__ __launch_bounds__(256) void gat_gather1_k(
    const int* __restrict__ rowptr, const int* __restrict__ csr,
    const float* __restrict__ alps, const float* __restrict__ alpd,
    const float* __restrict__ x, float* __restrict__ agg) {
  int wid2 = (blockIdx.x * 256 + threadIdx.x) >> 6;
  int lane = threadIdx.x & 63;
  int half = lane >> 5, l = lane & 31;
  int n = wid2 * 2 + half;
  bool valid = n < N_NODES;
  int beg = valid ? rowptr[n] : 0;
  int end = valid ? rowptr[n + 1] : 0;
  float4 ad4 = make_float4(0.f, 0.f, 0.f, 0.f);
  if (valid) ad4 = *(const float4*)(alpd + n * 4);
  float m[4], den[4], acc[4];
  #pragma unroll
  for (int h = 0; h < 4; ++h) { m[h] = -1e30f; den[h] = 0.f; acc[h] = 0.f; }

  for (int i = beg; i < end; i += 4) {
    int s[4]; bool ok[4]; float4 al[4]; float xv[4];
    #pragma unroll
    for (int j = 0; j < 4; ++j) { ok[j] = (i + j) < end; s[j] = ok[j] ? csr[i + j] : 0; }
    #pragma unroll
    for (int j = 0; j < 4; ++j) al[j] = *(const float4*)(alps + s[j] * 4);
    #pragma unroll
    for (int j = 0; j < 4; ++j) xv[j] = x[(size_t)s[j] * IN_DIM + l];
    #pragma unroll
    for (int h = 0; h < 4; ++h) {
      float v[4];
      #pragma unroll
      for (int j = 0; j < 4; ++j) {
        float t = ((const float*)&al[j])[h] + ((const float*)&ad4)[h];
        t = fmaxf(t, NEG_SLOPE * t);
        v[j] = ok[j] ? t : -1e30f;
      }
      float mn = fmaxf(fmaxf(fmaxf(v[0], v[1]), fmaxf(v[2], v[3])), m[h]);
      float c  = ex2(m[h] - mn);
      float e0 = ex2(v[0] - mn), e1 = ex2(v[1] - mn);
      float e2 = ex2(v[2] - mn), e3 = ex2(v[3] - mn);
      den[h] = den[h] * c + (e0 + e1) + (e2 + e3);
      acc[h] = acc[h] * c + e0 * xv[0] + e1 * xv[1] + e2 * xv[2] + e3 * xv[3];
      m[h] = mn;
    }
  }
  if (valid) {
    #pragma unroll
    for (int h = 0; h < 4; ++h)
      agg[(size_t)n * 128 + h * 32 + l] = acc[h] / (den[h] + 1e-16f);
  }
}

// out1 = relu(agg @ W1_head + b1), emitted as SPLIT bf16 (hi/lo) for the MFMA gemm
__global__ __launch_bounds__(256) void gemm_head1(const float* __restrict__ agg,
                                                  const float* __restrict__ W,
                                                  const float* __restrict__ b,
                                                  unsigned short* __restrict__ Ahi,
                                                  unsigned short* __restrict__ Alo) {
  __shared__ float As[32][68];
  __shared__ float Bs[32][64];
  const int row0 = blockIdx.x * 64;
  const int q = blockIdx.y;
  const int col0 = q * 64;
  const int t = threadIdx.x, tx = t & 15, ty = t >> 4;
  #pragma unroll
  for (int i = 0; i < 2; ++i) {
    int idx = t + i * 256;
    int r = idx >> 3, k4 = idx & 7;
    int rr = row0 + r;
    float4 a = make_float4(0.f, 0.f, 0.f, 0.f);
    if (rr < N_NODES) a = *(const float4*)(agg + (size_t)rr * 128 + q * 32 + k4 * 4);
    As[k4 * 4 + 0][r] = a.x;
    As[k4 * 4 + 1][r] = a.y;
    As[k4 * 4 + 2][r] = a.z;
    As[k4 * 4 + 3][r] = a.w;
  }
  #pragma unroll
  for (int i = 0; i < 2; ++i) {
    int idx = t + i * 256;
    int k = idx >> 4, c4 = idx & 15;
    *(float4*)&Bs[k][c4 * 4] = *(const float4*)(W + (size_t)k * D + col0 + c4 * 4);
  }
  __syncthreads();
  float acc[4][4] = {{0.f}};
  #pragma unroll
  for (int k = 0; k < 32; ++k) {
    float4 av = *(const float4*)&As[k][ty * 4];
    float4 bv = *(const float4*)&Bs[k][tx * 4];
    acc[0][0] += av.x * bv.x; acc[0][1] += av.x * bv.y;
    acc[0][2] += av.x * bv.z; acc[0][3] += av.x * bv.w;
    acc[1][0] += av.y * bv.x; acc[1][1] += av.y * bv.y;
    acc[1][2] += av.y * bv.z; acc[1][3] += av.y * bv.w;
    acc[2][0] += av.z * bv.x; acc[2][1] += av.z * bv.y;
    acc[2][2] += av.z * bv.z; acc[2][3] += av.z * bv.w;
    acc[3][0] += av.w * bv.x; acc[3][1] += av.w * bv.y;
    acc[3][2] += av.w * bv.z; acc[3][3] += av.w * bv.w;
  }
  float4 bv = *(const float4*)(b + col0 + tx * 4);
  const float bb[4] = {bv.x, bv.y, bv.z, bv.w};
  #pragma unroll
  for (int i = 0; i < 4; ++i) {
    int rr = row0 + ty * 4 + i;
    if (rr < N_NODES) {
      ushort4 hi, lo;
      unsigned short* hp = (unsigned short*)&hi;
      unsigned short* lp = (unsigned short*)&lo;
      #pragma unroll
      for (int j = 0; j < 4; ++j) {
        float o = fmaxf(acc[i][j] + bb[j], 0.f);
        unsigned short h = bf16_rne(o);
        hp[j] = h;
        lp[j] = bf16_rne(o - bf16f(h));
      }
      *(ushort4*)(Ahi + (size_t)rr * D + col0 + tx * 4) = hi;
      *(ushort4*)(Alo + (size_t)rr * D + col0 + tx * 4) = lo;
    }
  }
}

// ===== layer-2 GEMM via split-bf16 MFMA; h2 emitted as fp16 for the gather =====
__global__ __launch_bounds__(256) void gemm2_mfma(
    const unsigned short* __restrict__ Ahi, const unsigned short* __restrict__ Alo,
    const unsigned short* __restrict__ Whi, const unsigned short* __restrict__ Wlo,
    const float* __restrict__ asrc, const float* __restrict__ adst,
    _Float16* __restrict__ h2, float* __restrict__ alps, float* __restrict__ alpd) {
  __shared__ __attribute__((aligned(16))) unsigned short As_hi[128][40];
  __shared__ __attribute__((aligned(16))) unsigned short As_lo[128][40];
  __shared__ __attribute__((aligned(16))) unsigned short Bs_hi[128][40];
  __shared__ __attribute__((aligned(16))) unsigned short Bs_lo[128][40];
  const int row0 = blockIdx.x * 128;
  const int col0 = blockIdx.y * 128;
  const int t = threadIdx.x;
  const int wave = t >> 6, lane = t & 63;
  const int wr = wave >> 1, wc = wave & 1;
  const int lg = lane >> 4, li = lane & 15;

  f32x4 acc[4][4];
  #pragma unroll
  for (int m = 0; m < 4; ++m)
    #pragma unroll
    for (int n = 0; n < 4; ++n) acc[m][n] = (f32x4)0.f;

  for (int kc = 0; kc < D; kc += 32) {
    #pragma unroll
    for (int i = 0; i < 2; ++i) {
      int idx = t + i * 256;          // 0..511
      int r = idx >> 2, seg = idx & 3;
      int rr = row0 + r;
      uint4 vh = make_uint4(0, 0, 0, 0), vl = make_uint4(0, 0, 0, 0);
      if (rr < N_NODES) {
        vh = *(const uint4*)(Ahi + (size_t)rr * D + kc + seg * 8);
        vl = *(const uint4*)(Alo + (size_t)rr * D + kc + seg * 8);
      }
      *(uint4*)&As_hi[r][seg * 8] = vh;
      *(uint4*)&As_lo[r][seg * 8] = vl;
      uint4 wh = *(const uint4*)(Whi + (size_t)(col0 + r) * D + kc + seg * 8);
      uint4 wl = *(const uint4*)(Wlo + (size_t)(col0 + r) * D + kc + seg * 8);
      *(uint4*)&Bs_hi[r][seg * 8] = wh;
      *(uint4*)&Bs_lo[r][seg * 8] = wl;
    }
    __syncthreads();
    s16x8 ah[4], al[4], bh[4], bl[4];
    #pragma unroll
    for (int m = 0; m < 4; ++m) {
      int r = wr * 64 + m * 16 + li;
      ah[m] = *(const s16x8*)&As_hi[r][lg * 8];
      al[m] = *(const s16x8*)&As_lo[r][lg * 8];
    }
    #pragma unroll
    for (int n = 0; n < 4; ++n) {
      int c = wc * 64 + n * 16 + li;
      bh[n] = *(const s16x8*)&Bs_hi[c][lg * 8];
      bl[n] = *(const s16x8*)&Bs_lo[c][lg * 8];
    }
    #pragma unroll
    for (int m = 0; m < 4; ++m) {
      #pragma unroll
      for (int n = 0; n < 4; ++n) {
        acc[m][n] = __builtin_amdgcn_mfma_f32_16x16x32_bf16(ah[m], bh[n], acc[m][n], 0, 0, 0);
        acc[m][n] = __builtin_amdgcn_mfma_f32_16x16x32_bf16(ah[m], bl[n], acc[m][n], 0, 0, 0);
        acc[m][n] = __builtin_amdgcn_mfma_f32_16x16x32_bf16(al[m], bh[n], acc[m][n], 0, 0, 0);
      }
    }
    __syncthreads();
  }

  // store h2 tile as fp16
  #pragma unroll
  for (int m = 0; m < 4; ++m) {
    #pragma unroll
    for (int reg = 0; reg < 4; ++reg) {
      int rr = row0 + wr * 64 + m * 16 + lg * 4 + reg;
      if (rr < N_NODES) {
        #pragma unroll
        for (int n = 0; n < 4; ++n)
          h2[(size_t)rr * D + col0 + wc * 64 + n * 16 + li] = (_Float16)acc[m][n][reg];
      }
    }
  }

  // fused attention logits (fp32 accumulators): this wave's 64 cols == head q
  const int q = blockIdx.y * 2 + wc;
  float wsv[4], wdv[4];
  #pragma unroll
  for (int n = 0; n < 4; ++n) {
    wsv[n] = asrc[q * HID + n * 16 + li];
    wdv[n] = adst[q * HID + n * 16 + li];
  }
  #pragma unroll
  for (int m = 0; m < 4; ++m) {
    #pragma unroll
    for (int reg = 0; reg < 4; ++reg) {
      float ps = acc[m][0][reg] * wsv[0] + acc[m][1][reg] * wsv[1]
               + acc[m][2][reg] * wsv[2] + acc[m][3][reg] * wsv[3];
      float pd = acc[m][0][reg] * wdv[0] + acc[m][1][reg] * wdv[1]
               + acc[m][2][reg] * wdv[2] + acc[m][3][reg] * wdv[3];
      #pragma unroll
      for (int off = 1; off < 16; off <<= 1) {
        ps += __shfl_xor(ps, off);
        pd += __shfl_xor(pd, off);
      }
      int rr = row0 + wr * 64 + m * 16 + lg * 4 + reg;
      if (li == 0 && rr < N_NODES) {
        alps[rr * HEADS + q] = ps * LOG2E;
        alpd[rr * HEADS + q] = pd * LOG2E;
      }
    }
  }
}

// ====== layer-2 gather: 2 nodes/wave, 8 ch/lane, fused pair-head GEMV ======
// half-wave (32 lanes) per node; lane l owns channels 8l..8l+7 (head q = l>>3).
// Per-edge logit math now advances 2 edges per wave-instruction (was 1).
__global__ __launch_bounds__(256) void gat_gather2_k(
    const int* __restrict__ rowptr, const int* __restrict__ csr,
    const float* __restrict__ alps, const float* __restrict__ alpd,
    const _Float16* __restrict__ h, const float* __restrict__ b,
    const float* __restrict__ hw,
    float* __restrict__ u, float* __restrict__ v) {
  int wid2 = (blockIdx.x * 256 + threadIdx.x) >> 6;
  int lane = threadIdx.x & 63;
  int half = lane >> 5, l = lane & 31;
  int n = wid2 * 2 + half;
  bool valid = n < N_NODES;
  int q = l >> 3;                      // head of my 8 channels
  int beg = valid ? rowptr[n] : 0;
  int end = valid ? rowptr[n + 1] : 0;
  float ad = valid ? alpd[n * HEADS + q] : 0.f;

  float m = -1e30f, den = 0.f;
  float acc[8] = {0.f, 0.f, 0.f, 0.f, 0.f, 0.f, 0.f, 0.f};

  for (int i = beg; i < end; i += 4) {
    int s[4]; bool ok[4]; float xl[4]; f16x8 hv[4];
    #pragma unroll
    for (int j = 0; j < 4; ++j) { ok[j] = (i + j) < end; s[j] = ok[j] ? csr[i + j] : 0; }
    #pragma unroll
    for (int j = 0; j < 4; ++j) xl[j] = alps[s[j] * HEADS + q];
    #pragma unroll
    for (int j = 0; j < 4; ++j) hv[j] = *(const f16x8*)(h + (size_t)s[j] * D + l * 8);
    float vv[4];
    #pragma unroll
    for (int j = 0; j < 4; ++j) {
      float t = xl[j] + ad;
      t = fmaxf(t, NEG_SLOPE * t);
      vv[j] = ok[j] ? t : -1e30f;
    }
    float mn = fmaxf(m, fmaxf(fmaxf(vv[0], vv[1]), fmaxf(vv[2], vv[3])));
    float c = ex2(m - mn);
    float e0 = ex2(vv[0] - mn), e1 = ex2(vv[1] - mn);
    float e2 = ex2(vv[2] - mn), e3 = ex2(vv[3] - mn);
    den = den * c + (e0 + e1) + (e2 + e3);
    #pragma unroll
    for (int ch = 0; ch < 8; ++ch) {
      float a = acc[ch] * c;
      a = fmaf((float)hv[0][ch], e0, a);
      a = fmaf((float)hv[1][ch], e1, a);
      a = fmaf((float)hv[2][ch], e2, a);
      a = fmaf((float)hv[3][ch], e3, a);
      acc[ch] = a;
    }
    m = mn;
  }

  float inv = 1.f / (den + 1e-16f);
  float4 b0 = *(const float4*)(b + l * 8);
  float4 b1 = *(const float4*)(b + l * 8 + 4);
  float4 w00 = *(const float4*)(hw + l * 8);
  float4 w01 = *(const float4*)(hw + l * 8 + 4);
  float4 w10 = *(const float4*)(hw + D + l * 8);
  float4 w11 = *(const float4*)(hw + D + l * 8 + 4);
  const float* bb[2] = {(const float*)&b0, (const float*)&b1};
  const float* w0p[2] = {(const float*)&w00, (const float*)&w01};
  const float* w1p[2] = {(const float*)&w10, (const float*)&w11};
  float su = 0.f, sv = 0.f;
  #pragma unroll
  for (int ch = 0; ch < 8; ++ch) {
    float o = fmaxf(acc[ch] * inv + bb[ch >> 2][ch & 3], 0.f);
    su = fmaf(o, w0p[ch >> 2][ch & 3], su);
    sv = fmaf(o, w1p[ch >> 2][ch & 3], sv);
  }
  #pragma unroll
  for (int off = 16; off; off >>= 1) {    // xor masks <32 stay within the half
    su += __shfl_xor(su, off);
    sv += __shfl_xor(sv, off);
  }
  if (l == 0 && valid) { u[n] = su; v[n] = sv; }
}

// ---- pair lookup: out[p] = u[a] + v[b] + hb ----
__global__ void pair_lu_k(const int* __restrict__ pairs,
                          const float* __restrict__ u, const float* __restrict__ v,
                          const float* __restrict__ hb, float* __restrict__ out) {
  int g = blockIdx.x * 256 + threadIdx.x;
  if (g >= P_PAIRS) return;
  int a = pairs[g * 2], b = pairs[g * 2 + 1];
  out[g] = u[a] + v[b] + hb[0];
}

extern "C" void kernel_launch(void* const* d_in, const int* in_sizes, int n_in,
                              void* d_out, int out_size, void* d_ws, size_t ws_size,
                              hipStream_t stream) {
  const float* x    = (const float*)d_in[0];
  const int*   ei   = (const int*)d_in[1];
  const int*   prs  = (const int*)d_in[2];
  const float* W1   = (const float*)d_in[3];
  const float* as1  = (const float*)d_in[4];
  const float* ad1  = (const float*)d_in[5];
  const float* b1   = (const float*)d_in[6];
  const float* W2   = (const float*)d_in[7];
  const float* as2  = (const float*)d_in[8];
  const float* ad2  = (const float*)d_in[9];
  const float* b2   = (const float*)d_in[10];
  const float* hw   = (const float*)d_in[11];
  const float* hb   = (const float*)d_in[12];
  float* out = (float*)d_out;

  const int NPAD = 50048;   // 391*128

  char* w = (char*)d_ws;
  float* buf0 = (float*)w;             w += (size_t)N_NODES * D * 4;     // agg1 [n][128] / h2 fp16 [n][256]
  float* alps = (float*)w;             w += (size_t)N_NODES * HEADS * 4;
  float* alpd = (float*)w;             w += (size_t)N_NODES * HEADS * 4;
  int* rowptr = (int*)w;               w += (size_t)(N_NODES + 1) * 4;
  int* csr    = (int*)w;               w += (size_t)E_TOT * 4;
  float* uu   = (float*)w;             w += (size_t)N_NODES * 4;
  float* vv   = (float*)w;             w += (size_t)N_NODES * 4;
  float* wa_s = (float*)w;             w += 128 * 4;
  float* wa_d = (float*)w;             w += 128 * 4;
  unsigned short* Ahi = (unsigned short*)w;  w += (size_t)NPAD * D * 2;  // out1 bf16 hi
  unsigned short* Alo = (unsigned short*)w;  w += (size_t)NPAD * D * 2;  // out1 bf16 lo
  unsigned short* Whi = (unsigned short*)w;  w += (size_t)D * D * 2;     // W2T hi
  unsigned short* Wlo = (unsigned short*)w;  w += (size_t)D * D * 2;     // W2T lo

  _Float16* h2f16 = (_Float16*)buf0;

  // CSR-build temporaries aliased into buf0 (first real write to buf0 is
  // gat_gather1_k, which runs strictly after scatter_k on this stream)
  int* deg      = (int*)buf0;
  int* pos      = deg + N_NODES;
  int* scan_out = pos + N_NODES;
  int* bsum     = scan_out + N_NODES;

  const int eBlk     = (E_TOT + 255) / 256;               // 3321
  const int nScanBlk = (N_NODES + SCAN_BS - 1) / SCAN_BS; // 49
  const int nBlk256  = (N_NODES + 255) / 256;             // 196
  const int a1Blk    = (N_NODES * 8 + 255) / 256;         // 1563
  const int g1Blk    = ((N_NODES + 1) / 2 * 64 + 255) / 256; // 6250 (2 nodes/wave)
  const int pairBlk  = (P_PAIRS + 255) / 256;             // 782
  const dim3 headGrid((N_NODES + 63) / 64, HEADS);        // 782 x 4 (K=32 GEMM)
  const dim3 mfmaGrid(NPAD / 128, D / 128);               // 391 x 2

  // ---------- CSR build (once, reused by both layers) ----------
  hipMemsetAsync(deg, 0, (size_t)2 * N_NODES * 4, stream);  // deg + pos in one memset
  count_k<<<eBlk, 256, 0, stream>>>(ei, deg);
  scan_block_k<<<nScanBlk, SCAN_BS, 0, stream>>>(deg, scan_out, bsum, N_NODES);
  scan_top_k<<<1, 256, 0, stream>>>(bsum, nScanBlk);
  add_off_k<<<nBlk256, 256, 0, stream>>>(scan_out, bsum, rowptr);
  scatter_k<<<eBlk, 256, 0, stream>>>(ei, rowptr, pos, csr);

  // ---------- weight prep ----------
  prep_wa1_k<<<1, 256, 0, stream>>>(W1, as1, ad1, wa_s, wa_d);
  prep_w2t_k<<<D * D / 256, 256, 0, stream>>>(W2, Whi, Wlo);

  // ---------- layer 1 (x-space aggregation) ----------
  alphas1_k<<<a1Blk, 256, 0, stream>>>(x, wa_s, wa_d, alps, alpd);
  gat_gather1_k<<<g1Blk, 256, 0, stream>>>(rowptr, csr, alps, alpd, x, buf0);
  gemm_head1<<<headGrid, 256, 0, stream>>>(buf0, W1, b1, Ahi, Alo);

  // ---------- layer 2 (split-bf16 MFMA GEMM + fp16 gather w/ fused pair head) ----------
  gemm2_mfma<<<mfmaGrid, 256, 0, stream>>>(Ahi, Alo, Whi, Wlo, as2, ad2,
                                           h2f16, alps, alpd);
  gat_gather2_k<<<g1Blk, 256, 0, stream>>>(rowptr, csr, alps, alpd, h2f16, b2, hw, uu, vv);

  // ---------- pair head ----------
  pair_lu_k<<<pairBlk, 256, 0, stream>>>(prs, uu, vv, hb, out);
}

// Round 12
// 356.455 us; speedup vs baseline: 1.0995x; 1.0995x over previous
//
#include <hip/hip_runtime.h>

#define N_NODES 50000
#define E_EDGES 800000
#define E_TOT   (E_EDGES + N_NODES)   // edges + self loops
#define P_PAIRS 200000
#define IN_DIM  32
#define HID     64
#define HEADS   4
#define D       256
#define NEG_SLOPE 0.2f
#define SCAN_BS 1024
#define LOG2E 1.4426950408889634f

typedef float    f32x4 __attribute__((ext_vector_type(4)));
typedef _Float16 h16x8 __attribute__((ext_vector_type(8)));
typedef _Float16 h16x4 __attribute__((ext_vector_type(4)));

__device__ __forceinline__ float ex2(float v) { return __builtin_amdgcn_exp2f(v); }

__device__ __forceinline__ void edge_sd(const int* __restrict__ ei, int e, int& s, int& d) {
  if (e < E_EDGES) { s = ei[e]; d = ei[E_EDGES + e]; }
  else             { s = d = e - E_EDGES; }
}

// ================= CSR build (dst-grouped) =================
__global__ void count_k(const int* __restrict__ ei, int* __restrict__ deg) {
  int e = blockIdx.x * 256 + threadIdx.x;
  if (e >= E_TOT) return;
  int s, d; edge_sd(ei, e, s, d);
  atomicAdd(&deg[d], 1);
}

__global__ __launch_bounds__(SCAN_BS) void scan_block_k(const int* __restrict__ in,
                                                        int* __restrict__ out,
                                                        int* __restrict__ bsum, int n) {
  __shared__ int tmp[SCAN_BS];
  int g = blockIdx.x * SCAN_BS + threadIdx.x;
  tmp[threadIdx.x] = (g < n) ? in[g] : 0;
  __syncthreads();
  for (int off = 1; off < SCAN_BS; off <<= 1) {
    int t = 0;
    if ((int)threadIdx.x >= off) t = tmp[threadIdx.x - off];
    __syncthreads();
    if ((int)threadIdx.x >= off) tmp[threadIdx.x] += t;
    __syncthreads();
  }
  if (g < n) out[g] = tmp[threadIdx.x];
  if (threadIdx.x == SCAN_BS - 1) bsum[blockIdx.x] = tmp[SCAN_BS - 1];
}

__global__ void scan_top_k(int* __restrict__ bsum, int nb) {
  __shared__ int tmp[256];
  tmp[threadIdx.x] = ((int)threadIdx.x < nb) ? bsum[threadIdx.x] : 0;
  __syncthreads();
  for (int off = 1; off < 256; off <<= 1) {
    int t = 0;
    if ((int)threadIdx.x >= off) t = tmp[threadIdx.x - off];
    __syncthreads();
    if ((int)threadIdx.x >= off) tmp[threadIdx.x] += t;
    __syncthreads();
  }
  if ((int)threadIdx.x < nb) bsum[threadIdx.x] = tmp[threadIdx.x];
}

__global__ void add_off_k(const int* __restrict__ scan_out,
                          const int* __restrict__ bsum,
                          int* __restrict__ rowptr) {
  int g = blockIdx.x * 256 + threadIdx.x;
  if (g >= N_NODES) return;
  int blk = g / SCAN_BS;
  int add = blk ? bsum[blk - 1] : 0;
  rowptr[g + 1] = scan_out[g] + add;
  if (g == 0) rowptr[0] = 0;
}

__global__ void scatter_k(const int* __restrict__ ei,
                          const int* __restrict__ rowptr,
                          int* __restrict__ pos, int* __restrict__ csr) {
  int e = blockIdx.x * 256 + threadIdx.x;
  if (e >= E_TOT) return;
  int s, d; edge_sd(ei, e, s, d);
  int idx = rowptr[d] + atomicAdd(&pos[d], 1);
  csr[idx] = s;
}

// ================ weight prep ================
__global__ void prep_wa1_k(const float* __restrict__ W1,
                           const float* __restrict__ as1,
                           const float* __restrict__ ad1,
                           float* __restrict__ wa_s, float* __restrict__ wa_d) {
  int t = threadIdx.x;                  // one block of 256
  int kk = (t >> 2) & 31, h = t & 3;
  const float* att = (t < 128) ? as1 : ad1;
  float sum = 0.f;
  for (int c = 0; c < HID; ++c) sum += W1[kk * D + h * HID + c] * att[h * HID + c];
  float* dst = (t < 128) ? wa_s : wa_d;
  dst[kk * 4 + h] = sum * LOG2E;
}

// W2T fp16: Wt[col][k] = (fp16) W2[k][col]
__global__ void prep_w2t_k(const float* __restrict__ W2,
                           _Float16* __restrict__ Wt) {
  int g = blockIdx.x * 256 + threadIdx.x;   // 65536
  int col = g >> 8, k = g & 255;
  Wt[g] = (_Float16)W2[(size_t)k * D + col];
}

// alps1[n,h] = x[n] . wa_s[:,h] ; 8 lanes per node, 8 nodes per wave
__global__ __launch_bounds__(256) void alphas1_k(const float* __restrict__ x,
                                                 const float* __restrict__ wa_s,
                                                 const float* __restrict__ wa_d,
                                                 float* __restrict__ alps,
                                                 float* __restrict__ alpd) {
  int w = (blockIdx.x * 256 + threadIdx.x) >> 6;
  int lane = threadIdx.x & 63;
  int n = w * 8 + (lane >> 3);
  int j = lane & 7;
  float4 xv = make_float4(0.f, 0.f, 0.f, 0.f);
  if (n < N_NODES) xv = *(const float4*)(x + (size_t)n * IN_DIM + j * 4);
  float ps[4] = {0.f, 0.f, 0.f, 0.f}, pd[4] = {0.f, 0.f, 0.f, 0.f};
  #pragma unroll
  for (int kk = 0; kk < 4; ++kk) {
    float xk = ((const float*)&xv)[kk];
    float4 ws = *(const float4*)(wa_s + (j * 4 + kk) * 4);
    float4 wd = *(const float4*)(wa_d + (j * 4 + kk) * 4);
    ps[0] += xk * ws.x; ps[1] += xk * ws.y; ps[2] += xk * ws.z; ps[3] += xk * ws.w;
    pd[0] += xk * wd.x; pd[1] += xk * wd.y; pd[2] += xk * wd.z; pd[3] += xk * wd.w;
  }
  #pragma unroll
  for (int off = 1; off < 8; off <<= 1) {
    #pragma unroll
    for (int h = 0; h < 4; ++h) {
      ps[h] += __shfl_xor(ps[h], off);
      pd[h] += __shfl_xor(pd[h], off);
    }
  }
  if (j == 0 && n < N_NODES) {
    *(float4*)(alps + n * 4) = make_float4(ps[0], ps[1], ps[2], ps[3]);
    *(float4*)(alpd + n * 4) = make_float4(pd[0], pd[1], pd[2], pd[3]);
  }
}

// x-space gather, NO online max (logits bounded; unnormalized exp2 softmax):
// agg[n][h][k<32] = (sum_e exp2(leaky(logit)) * x[src][k]) / den[h]
__global__ __launch_bounds__(256) void gat_gather1_k(
    const int* __restrict__ rowptr, const int* __restrict__ csr,
    const float* __restrict__ alps, const float* __restrict__ alpd,
    const float* __restrict__ x, float* __restrict__ agg) {
  int wid2 = (blockIdx.x * 256 + threadIdx.x) >> 6;
  int lane = threadIdx.x & 63;
  int half = lane >> 5, l = lane & 31;
  int n = wid2 * 2 + half;
  bool valid = n < N_NODES;
  int beg = valid ? rowptr[n] : 0;
  int end = valid ? rowptr[n + 1] : 0;
  float4 ad4 = make_float4(0.f, 0.f, 0.f, 0.f);
  if (valid) ad4 = *(const float4*)(alpd + n * 4);
  float den[4] = {0.f, 0.f, 0.f, 0.f}, acc[4] = {0.f, 0.f, 0.f, 0.f};

  for (int i = beg; i < end; i += 4) {
    int s[4]; bool ok[4]; float4 al[4]; float xv[4];
    #pragma unroll
    for (int j = 0; j < 4; ++j) { ok[j] = (i + j) < end; s[j] = ok[j] ? csr[i + j] : 0; }
    #pragma unroll
    for (int j = 0; j < 4; ++j) al[j] = *(const float4*)(alps + s[j] * 4);
    #pragma unroll
    for (int j = 0; j < 4; ++j) xv[j] = x[(size_t)s[j] * IN_DIM + l];
    #pragma unroll
    for (int h = 0; h < 4; ++h) {
      float e[4];
      #pragma unroll
      for (int j = 0; j < 4; ++j) {
        float t = ((const float*)&al[j])[h] + ((const float*)&ad4)[h];
        t = fmaxf(t, NEG_SLOPE * t);
        e[j] = ok[j] ? ex2(t) : 0.f;
      }
      den[h] += (e[0] + e[1]) + (e[2] + e[3]);
      float a = acc[h];
      a = fmaf(e[0], xv[0], a);
      a = fmaf(e[1], xv[1], a);
      a = fmaf(e[2], xv[2], a);
      a = fmaf(e[3], xv[3], a);
      acc[h] = a;
    }
  }
  if (valid) {
    #pragma unroll
    for (int h = 0; h < 4; ++h)
      agg[(size_t)n * 128 + h * 32 + l] = acc[h] / (den[h] + 1e-16f);
  }
}

// out1 = relu(agg @ W1_head + b1), emitted as fp16 for the MFMA gemm
__global__ __launch_bounds__(256) void gemm_head1(const float* __restrict__ agg,
                                                  const float* __restrict__ W,
                                                  const float* __restrict__ b,
                                                  _Float16* __restrict__ A16) {
  __shared__ float As[32][68];
  __shared__ float Bs[32][64];
  const int row0 = blockIdx.x * 64;
  const int q = blockIdx.y;
  const int col0 = q * 64;
  const int t = threadIdx.x, tx = t & 15, ty = t >> 4;
  #pragma unroll
  for (int i = 0; i < 2; ++i) {
    int idx = t + i * 256;
    int r = idx >> 3, k4 = idx & 7;
    int rr = row0 + r;
    float4 a = make_float4(0.f, 0.f, 0.f, 0.f);
    if (rr < N_NODES) a = *(const float4*)(agg + (size_t)rr * 128 + q * 32 + k4 * 4);
    As[k4 * 4 + 0][r] = a.x;
    As[k4 * 4 + 1][r] = a.y;
    As[k4 * 4 + 2][r] = a.z;
    As[k4 * 4 + 3][r] = a.w;
  }
  #pragma unroll
  for (int i = 0; i < 2; ++i) {
    int idx = t + i * 256;
    int k = idx >> 4, c4 = idx & 15;
    *(float4*)&Bs[k][c4 * 4] = *(const float4*)(W + (size_t)k * D + col0 + c4 * 4);
  }
  __syncthreads();
  float acc[4][4] = {{0.f}};
  #pragma unroll
  for (int k = 0; k < 32; ++k) {
    float4 av = *(const float4*)&As[k][ty * 4];
    float4 bv = *(const float4*)&Bs[k][tx * 4];
    acc[0][0] += av.x * bv.x; acc[0][1] += av.x * bv.y;
    acc[0][2] += av.x * bv.z; acc[0][3] += av.x * bv.w;
    acc[1][0] += av.y * bv.x; acc[1][1] += av.y * bv.y;
    acc[1][2] += av.y * bv.z; acc[1][3] += av.y * bv.w;
    acc[2][0] += av.z * bv.x; acc[2][1] += av.z * bv.y;
    acc[2][2] += av.z * bv.z; acc[2][3] += av.z * bv.w;
    acc[3][0] += av.w * bv.x; acc[3][1] += av.w * bv.y;
    acc[3][2] += av.w * bv.z; acc[3][3] += av.w * bv.w;
  }
  float4 bv = *(const float4*)(b + col0 + tx * 4);
  const float bb[4] = {bv.x, bv.y, bv.z, bv.w};
  #pragma unroll
  for (int i = 0; i < 4; ++i) {
    int rr = row0 + ty * 4 + i;
    if (rr < N_NODES) {
      h16x4 o4;
      #pragma unroll
      for (int j = 0; j < 4; ++j)
        o4[j] = (_Float16)fmaxf(acc[i][j] + bb[j], 0.f);
      *(h16x4*)(A16 + (size_t)rr * D + col0 + tx * 4) = o4;
    }
  }
}

// ===== layer-2 GEMM via fp16 MFMA (single product); h2 out fp16, logits fp32 =====
__global__ __launch_bounds__(256) void gemm2_mfma(
    const _Float16* __restrict__ A16, const _Float16* __restrict__ Wt,
    const float* __restrict__ asrc, const float* __restrict__ adst,
    _Float16* __restrict__ h2, float* __restrict__ alps, float* __restrict__ alpd) {
  __shared__ __attribute__((aligned(16))) _Float16 As[128][40];
  __shared__ __attribute__((aligned(16))) _Float16 Bs[128][40];
  const int row0 = blockIdx.x * 128;
  const int col0 = blockIdx.y * 128;
  const int t = threadIdx.x;
  const int wave = t >> 6, lane = t & 63;
  const int wr = wave >> 1, wc = wave & 1;
  const int lg = lane >> 4, li = lane & 15;

  f32x4 acc[4][4];
  #pragma unroll
  for (int m = 0; m < 4; ++m)
    #pragma unroll
    for (int n = 0; n < 4; ++n) acc[m][n] = (f32x4)0.f;

  for (int kc = 0; kc < D; kc += 32) {
    #pragma unroll
    for (int i = 0; i < 2; ++i) {
      int idx = t + i * 256;          // 0..511
      int r = idx >> 2, seg = idx & 3;
      int rr = row0 + r;
      uint4 va = make_uint4(0, 0, 0, 0);
      if (rr < N_NODES) va = *(const uint4*)(A16 + (size_t)rr * D + kc + seg * 8);
      *(uint4*)&As[r][seg * 8] = va;
      uint4 vb = *(const uint4*)(Wt + (size_t)(col0 + r) * D + kc + seg * 8);
      *(uint4*)&Bs[r][seg * 8] = vb;
    }
    __syncthreads();
    h16x8 af[4], bf[4];
    #pragma unroll
    for (int m = 0; m < 4; ++m)
      af[m] = *(const h16x8*)&As[wr * 64 + m * 16 + li][lg * 8];
    #pragma unroll
    for (int n = 0; n < 4; ++n)
      bf[n] = *(const h16x8*)&Bs[wc * 64 + n * 16 + li][lg * 8];
    #pragma unroll
    for (int m = 0; m < 4; ++m)
      #pragma unroll
      for (int n = 0; n < 4; ++n)
        acc[m][n] = __builtin_amdgcn_mfma_f32_16x16x32_f16(af[m], bf[n], acc[m][n], 0, 0, 0);
    __syncthreads();
  }

  // store h2 tile as fp16
  #pragma unroll
  for (int m = 0; m < 4; ++m) {
    #pragma unroll
    for (int reg = 0; reg < 4; ++reg) {
      int rr = row0 + wr * 64 + m * 16 + lg * 4 + reg;
      if (rr < N_NODES) {
        #pragma unroll
        for (int n = 0; n < 4; ++n)
          h2[(size_t)rr * D + col0 + wc * 64 + n * 16 + li] = (_Float16)acc[m][n][reg];
      }
    }
  }

  // fused attention logits (fp32 accumulators): this wave's 64 cols == head q
  const int q = blockIdx.y * 2 + wc;
  float wsv[4], wdv[4];
  #pragma unroll
  for (int n = 0; n < 4; ++n) {
    wsv[n] = asrc[q * HID + n * 16 + li];
    wdv[n] = adst[q * HID + n * 16 + li];
  }
  #pragma unroll
  for (int m = 0; m < 4; ++m) {
    #pragma unroll
    for (int reg = 0; reg < 4; ++reg) {
      float ps = acc[m][0][reg] * wsv[0] + acc[m][1][reg] * wsv[1]
               + acc[m][2][reg] * wsv[2] + acc[m][3][reg] * wsv[3];
      float pd = acc[m][0][reg] * wdv[0] + acc[m][1][reg] * wdv[1]
               + acc[m][2][reg] * wdv[2] + acc[m][3][reg] * wdv[3];
      #pragma unroll
      for (int off = 1; off < 16; off <<= 1) {
        ps += __shfl_xor(ps, off);
        pd += __shfl_xor(pd, off);
      }
      int rr = row0 + wr * 64 + m * 16 + lg * 4 + reg;
      if (li == 0 && rr < N_NODES) {
        alps[rr * HEADS + q] = ps * LOG2E;
        alpd[rr * HEADS + q] = pd * LOG2E;
      }
    }
  }
}

// ====== layer-2 gather: 2 nodes/wave, 8 ch/lane, NO online max, 6-edge batch,
//        fused pair-head GEMV ======
__global__ __launch_bounds__(256) void gat_gather2_k(
    const int* __restrict__ rowptr, const int* __restrict__ csr,
    const float* __restrict__ alps, const float* __restrict__ alpd,
    const _Float16* __restrict__ h, const float* __restrict__ b,
    const float* __restrict__ hw,
    float* __restrict__ u, float* __restrict__ v) {
  int wid2 = (blockIdx.x * 256 + threadIdx.x) >> 6;
  int lane = threadIdx.x & 63;
  int half = lane >> 5, l = lane & 31;
  int n = wid2 * 2 + half;
  bool valid = n < N_NODES;
  int q = l >> 3;                      // head of my 8 channels
  int beg = valid ? rowptr[n] : 0;
  int end = valid ? rowptr[n + 1] : 0;
  float ad = valid ? alpd[n * HEADS + q] : 0.f;

  float den = 0.f;
  float acc[8] = {0.f, 0.f, 0.f, 0.f, 0.f, 0.f, 0.f, 0.f};

  for (int i = beg; i < end; i += 6) {
    int s[6]; bool ok[6]; float xl[6]; h16x8 hv[6];
    #pragma unroll
    for (int j = 0; j < 6; ++j) { ok[j] = (i + j) < end; s[j] = ok[j] ? csr[i + j] : 0; }
    #pragma unroll
    for (int j = 0; j < 6; ++j) xl[j] = alps[s[j] * HEADS + q];
    #pragma unroll
    for (int j = 0; j < 6; ++j) hv[j] = *(const h16x8*)(h + (size_t)s[j] * D + l * 8);
    float e[6];
    #pragma unroll
    for (int j = 0; j < 6; ++j) {
      float t = xl[j] + ad;
      t = fmaxf(t, NEG_SLOPE * t);
      e[j] = ok[j] ? ex2(t) : 0.f;
    }
    den += ((e[0] + e[1]) + (e[2] + e[3])) + (e[4] + e[5]);
    #pragma unroll
    for (int ch = 0; ch < 8; ++ch) {
      float a = acc[ch];
      a = fmaf((float)hv[0][ch], e[0], a);
      a = fmaf((float)hv[1][ch], e[1], a);
      a = fmaf((float)hv[2][ch], e[2], a);
      a = fmaf((float)hv[3][ch], e[3], a);
      a = fmaf((float)hv[4][ch], e[4], a);
      a = fmaf((float)hv[5][ch], e[5], a);
      acc[ch] = a;
    }
  }

  float inv = 1.f / (den + 1e-16f);
  float4 b0 = *(const float4*)(b + l * 8);
  float4 b1 = *(const float4*)(b + l * 8 + 4);
  float4 w00 = *(const float4*)(hw + l * 8);
  float4 w01 = *(const float4*)(hw + l * 8 + 4);
  float4 w10 = *(const float4*)(hw + D + l * 8);
  float4 w11 = *(const float4*)(hw + D + l * 8 + 4);
  const float* bb[2] = {(const float*)&b0, (const float*)&b1};
  const float* w0p[2] = {(const float*)&w00, (const float*)&w01};
  const float* w1p[2] = {(const float*)&w10, (const float*)&w11};
  float su = 0.f, sv = 0.f;
  #pragma unroll
  for (int ch = 0; ch < 8; ++ch) {
    float o = fmaxf(acc[ch] * inv + bb[ch >> 2][ch & 3], 0.f);
    su = fmaf(o, w0p[ch >> 2][ch & 3], su);
    sv = fmaf(o, w1p[ch >> 2][ch & 3], sv);
  }
  #pragma unroll
  for (int off = 16; off; off >>= 1) {    // xor masks <32 stay within the half
    su += __shfl_xor(su, off);
    sv += __shfl_xor(sv, off);
  }
  if (l == 0 && valid) { u[n] = su; v[n] = sv; }
}

// ---- pair lookup: out[p] = u[a] + v[b] + hb ----
__global__ void pair_lu_k(const int* __restrict__ pairs,
                          const float* __restrict__ u, const float* __restrict__ v,
                          const float* __restrict__ hb, float* __restrict__ out) {
  int g = blockIdx.x * 256 + threadIdx.x;
  if (g >= P_PAIRS) return;
  int a = pairs[g * 2], b = pairs[g * 2 + 1];
  out[g] = u[a] + v[b] + hb[0];
}

extern "C" void kernel_launch(void* const* d_in, const int* in_sizes, int n_in,
                              void* d_out, int out_size, void* d_ws, size_t ws_size,
                              hipStream_t stream) {
  const float* x    = (const float*)d_in[0];
  const int*   ei   = (const int*)d_in[1];
  const int*   prs  = (const int*)d_in[2];
  const float* W1   = (const float*)d_in[3];
  const float* as1  = (const float*)d_in[4];
  const float* ad1  = (const float*)d_in[5];
  const float* b1   = (const float*)d_in[6];
  const float* W2   = (const float*)d_in[7];
  const float* as2  = (const float*)d_in[8];
  const float* ad2  = (const float*)d_in[9];
  const float* b2   = (const float*)d_in[10];
  const float* hw   = (const float*)d_in[11];
  const float* hb   = (const float*)d_in[12];
  float* out = (float*)d_out;

  const int NPAD = 50048;   // 391*128

  char* w = (char*)d_ws;
  float* buf0 = (float*)w;             w += (size_t)N_NODES * D * 4;     // agg1 [n][128] / h2 fp16 [n][256]
  float* alps = (float*)w;             w += (size_t)N_NODES * HEADS * 4;
  float* alpd = (float*)w;             w += (size_t)N_NODES * HEADS * 4;
  int* rowptr = (int*)w;               w += (size_t)(N_NODES + 1) * 4;
  int* csr    = (int*)w;               w += (size_t)E_TOT * 4;
  float* uu   = (float*)w;             w += (size_t)N_NODES * 4;
  float* vv   = (float*)w;             w += (size_t)N_NODES * 4;
  float* wa_s = (float*)w;             w += 128 * 4;
  float* wa_d = (float*)w;             w += 128 * 4;
  _Float16* A16 = (_Float16*)w;        w += (size_t)NPAD * D * 2;        // out1 fp16
  _Float16* Wt  = (_Float16*)w;        w += (size_t)D * D * 2;           // W2T fp16

  _Float16* h2f16 = (_Float16*)buf0;

  // CSR-build temporaries aliased into buf0 (first real write to buf0 is
  // gat_gather1_k, which runs strictly after scatter_k on this stream)
  int* deg      = (int*)buf0;
  int* pos      = deg + N_NODES;
  int* scan_out = pos + N_NODES;
  int* bsum     = scan_out + N_NODES;

  const int eBlk     = (E_TOT + 255) / 256;               // 3321
  const int nScanBlk = (N_NODES + SCAN_BS - 1) / SCAN_BS; // 49
  const int nBlk256  = (N_NODES + 255) / 256;             // 196
  const int a1Blk    = (N_NODES * 8 + 255) / 256;         // 1563
  const int g1Blk    = ((N_NODES + 1) / 2 * 64 + 255) / 256; // 6250 (2 nodes/wave)
  const int pairBlk  = (P_PAIRS + 255) / 256;             // 782
  const dim3 headGrid((N_NODES + 63) / 64, HEADS);        // 782 x 4 (K=32 GEMM)
  const dim3 mfmaGrid(NPAD / 128, D / 128);               // 391 x 2

  // ---------- CSR build (once, reused by both layers) ----------
  hipMemsetAsync(deg, 0, (size_t)2 * N_NODES * 4, stream);  // deg + pos in one memset
  count_k<<<eBlk, 256, 0, stream>>>(ei, deg);
  scan_block_k<<<nScanBlk, SCAN_BS, 0, stream>>>(deg, scan_out, bsum, N_NODES);
  scan_top_k<<<1, 256, 0, stream>>>(bsum, nScanBlk);
  add_off_k<<<nBlk256, 256, 0, stream>>>(scan_out, bsum, rowptr);
  scatter_k<<<eBlk, 256, 0, stream>>>(ei, rowptr, pos, csr);

  // ---------- weight prep ----------
  prep_wa1_k<<<1, 256, 0, stream>>>(W1, as1, ad1, wa_s, wa_d);
  prep_w2t_k<<<D * D / 256, 256, 0, stream>>>(W2, Wt);

  // ---------- layer 1 (x-space aggregation) ----------
  alphas1_k<<<a1Blk, 256, 0, stream>>>(x, wa_s, wa_d, alps, alpd);
  gat_gather1_k<<<g1Blk, 256, 0, stream>>>(rowptr, csr, alps, alpd, x, buf0);
  gemm_head1<<<headGrid, 256, 0, stream>>>(buf0, W1, b1, A16);

  // ---------- layer 2 (fp16 MFMA GEMM + fp16 gather w/ fused pair head) ----------
  gemm2_mfma<<<mfmaGrid, 256, 0, stream>>>(A16, Wt, as2, ad2, h2f16, alps, alpd);
  gat_gather2_k<<<g1Blk, 256, 0, stream>>>(rowptr, csr, alps, alpd, h2f16, b2, hw, uu, vv);

  // ---------- pair head ----------
  pair_lu_k<<<pairBlk, 256, 0, stream>>>(prs, uu, vv, hb, out);
}

// Round 13
// 347.785 us; speedup vs baseline: 1.1269x; 1.0249x over previous
//
#include <hip/hip_runtime.h>

#define N_NODES 50000
#define E_EDGES 800000
#define E_TOT   (E_EDGES + N_NODES)   // edges + self loops
#define P_PAIRS 200000
#define IN_DIM  32
#define HID     64
#define HEADS   4
#define D       256
#define NEG_SLOPE 0.2f
#define SCAN_BS 1024
#define LOG2E 1.4426950408889634f

typedef float    f32x4 __attribute__((ext_vector_type(4)));
typedef _Float16 h16x8 __attribute__((ext_vector_type(8)));
typedef _Float16 h16x4 __attribute__((ext_vector_type(4)));

__device__ __forceinline__ float ex2(float v) { return __builtin_amdgcn_exp2f(v); }

__device__ __forceinline__ void edge_sd(const int* __restrict__ ei, int e, int& s, int& d) {
  if (e < E_EDGES) { s = ei[e]; d = ei[E_EDGES + e]; }
  else             { s = d = e - E_EDGES; }
}

// ================= CSR build (dst-grouped) =================
__global__ void count_k(const int* __restrict__ ei, int* __restrict__ deg) {
  int e = blockIdx.x * 256 + threadIdx.x;
  if (e >= E_TOT) return;
  int s, d; edge_sd(ei, e, s, d);
  atomicAdd(&deg[d], 1);
}

__global__ __launch_bounds__(SCAN_BS) void scan_block_k(const int* __restrict__ in,
                                                        int* __restrict__ out,
                                                        int* __restrict__ bsum, int n) {
  __shared__ int tmp[SCAN_BS];
  int g = blockIdx.x * SCAN_BS + threadIdx.x;
  tmp[threadIdx.x] = (g < n) ? in[g] : 0;
  __syncthreads();
  for (int off = 1; off < SCAN_BS; off <<= 1) {
    int t = 0;
    if ((int)threadIdx.x >= off) t = tmp[threadIdx.x - off];
    __syncthreads();
    if ((int)threadIdx.x >= off) tmp[threadIdx.x] += t;
    __syncthreads();
  }
  if (g < n) out[g] = tmp[threadIdx.x];
  if (threadIdx.x == SCAN_BS - 1) bsum[blockIdx.x] = tmp[SCAN_BS - 1];
}

__global__ void scan_top_k(int* __restrict__ bsum, int nb) {
  __shared__ int tmp[256];
  tmp[threadIdx.x] = ((int)threadIdx.x < nb) ? bsum[threadIdx.x] : 0;
  __syncthreads();
  for (int off = 1; off < 256; off <<= 1) {
    int t = 0;
    if ((int)threadIdx.x >= off) t = tmp[threadIdx.x - off];
    __syncthreads();
    if ((int)threadIdx.x >= off) tmp[threadIdx.x] += t;
    __syncthreads();
  }
  if ((int)threadIdx.x < nb) bsum[threadIdx.x] = tmp[threadIdx.x];
}

__global__ void add_off_k(const int* __restrict__ scan_out,
                          const int* __restrict__ bsum,
                          int* __restrict__ rowptr) {
  int g = blockIdx.x * 256 + threadIdx.x;
  if (g >= N_NODES) return;
  int blk = g / SCAN_BS;
  int add = blk ? bsum[blk - 1] : 0;
  rowptr[g + 1] = scan_out[g] + add;
  if (g == 0) rowptr[0] = 0;
}

__global__ void scatter_k(const int* __restrict__ ei,
                          const int* __restrict__ rowptr,
                          int* __restrict__ pos, int* __restrict__ csr) {
  int e = blockIdx.x * 256 + threadIdx.x;
  if (e >= E_TOT) return;
  int s, d; edge_sd(ei, e, s, d);
  int idx = rowptr[d] + atomicAdd(&pos[d], 1);
  csr[idx] = s;
}

// ================ weight prep ================
__global__ void prep_wa1_k(const float* __restrict__ W1,
                           const float* __restrict__ as1,
                           const float* __restrict__ ad1,
                           float* __restrict__ wa_s, float* __restrict__ wa_d) {
  int t = threadIdx.x;                  // one block of 256
  int kk = (t >> 2) & 31, h = t & 3;
  const float* att = (t < 128) ? as1 : ad1;
  float sum = 0.f;
  for (int c = 0; c < HID; ++c) sum += W1[kk * D + h * HID + c] * att[h * HID + c];
  float* dst = (t < 128) ? wa_s : wa_d;
  dst[kk * 4 + h] = sum * LOG2E;
}

// W2T fp16: Wt[col][k] = (fp16) W2[k][col]
__global__ void prep_w2t_k(const float* __restrict__ W2,
                           _Float16* __restrict__ Wt) {
  int g = blockIdx.x * 256 + threadIdx.x;   // 65536
  int col = g >> 8, k = g & 255;
  Wt[g] = (_Float16)W2[(size_t)k * D + col];
}

// alps1[n,h] = x[n] . wa_s[:,h] ; 8 lanes per node, 8 nodes per wave
__global__ __launch_bounds__(256) void alphas1_k(const float* __restrict__ x,
                                                 const float* __restrict__ wa_s,
                                                 const float* __restrict__ wa_d,
                                                 float* __restrict__ alps,
                                                 float* __restrict__ alpd) {
  int w = (blockIdx.x * 256 + threadIdx.x) >> 6;
  int lane = threadIdx.x & 63;
  int n = w * 8 + (lane >> 3);
  int j = lane & 7;
  float4 xv = make_float4(0.f, 0.f, 0.f, 0.f);
  if (n < N_NODES) xv = *(const float4*)(x + (size_t)n * IN_DIM + j * 4);
  float ps[4] = {0.f, 0.f, 0.f, 0.f}, pd[4] = {0.f, 0.f, 0.f, 0.f};
  #pragma unroll
  for (int kk = 0; kk < 4; ++kk) {
    float xk = ((const float*)&xv)[kk];
    float4 ws = *(const float4*)(wa_s + (j * 4 + kk) * 4);
    float4 wd = *(const float4*)(wa_d + (j * 4 + kk) * 4);
    ps[0] += xk * ws.x; ps[1] += xk * ws.y; ps[2] += xk * ws.z; ps[3] += xk * ws.w;
    pd[0] += xk * wd.x; pd[1] += xk * wd.y; pd[2] += xk * wd.z; pd[3] += xk * wd.w;
  }
  #pragma unroll
  for (int off = 1; off < 8; off <<= 1) {
    #pragma unroll
    for (int h = 0; h < 4; ++h) {
      ps[h] += __shfl_xor(ps[h], off);
      pd[h] += __shfl_xor(pd[h], off);
    }
  }
  if (j == 0 && n < N_NODES) {
    *(float4*)(alps + n * 4) = make_float4(ps[0], ps[1], ps[2], ps[3]);
    *(float4*)(alpd + n * 4) = make_float4(pd[0], pd[1], pd[2], pd[3]);
  }
}

// x-space gather, gather2-style lane economy: half-wave per node;
// lane l owns head q=l>>3 and x-channels kk=(l&7)*4 (float4 per edge).
// One exp2 per lane per edge (own head only). No online max (bounded logits).
__global__ __launch_bounds__(256) void gat_gather1_k(
    const int* __restrict__ rowptr, const int* __restrict__ csr,
    const float* __restrict__ alps, const float* __restrict__ alpd,
    const float* __restrict__ x, float* __restrict__ agg) {
  int wid2 = (blockIdx.x * 256 + threadIdx.x) >> 6;
  int lane = threadIdx.x & 63;
  int half = lane >> 5, l = lane & 31;
  int n = wid2 * 2 + half;
  bool valid = n < N_NODES;
  int q = l >> 3;                       // my head
  int kk = (l & 7) * 4;                 // my x-channel base
  int beg = valid ? rowptr[n] : 0;
  int end = valid ? rowptr[n + 1] : 0;
  float ad = valid ? alpd[n * HEADS + q] : 0.f;

  float den = 0.f;
  float4 acc = make_float4(0.f, 0.f, 0.f, 0.f);

  for (int i = beg; i < end; i += 6) {
    int s[6]; bool ok[6]; float xl[6]; float4 xv[6];
    #pragma unroll
    for (int j = 0; j < 6; ++j) { ok[j] = (i + j) < end; s[j] = ok[j] ? csr[i + j] : 0; }
    #pragma unroll
    for (int j = 0; j < 6; ++j) xl[j] = alps[s[j] * HEADS + q];
    #pragma unroll
    for (int j = 0; j < 6; ++j) xv[j] = *(const float4*)(x + (size_t)s[j] * IN_DIM + kk);
    float e[6];
    #pragma unroll
    for (int j = 0; j < 6; ++j) {
      float t = xl[j] + ad;
      t = fmaxf(t, NEG_SLOPE * t);
      e[j] = ok[j] ? ex2(t) : 0.f;
    }
    den += ((e[0] + e[1]) + (e[2] + e[3])) + (e[4] + e[5]);
    #pragma unroll
    for (int j = 0; j < 6; ++j) {
      acc.x = fmaf(e[j], xv[j].x, acc.x);
      acc.y = fmaf(e[j], xv[j].y, acc.y);
      acc.z = fmaf(e[j], xv[j].z, acc.z);
      acc.w = fmaf(e[j], xv[j].w, acc.w);
    }
  }
  if (valid) {
    float inv = 1.f / (den + 1e-16f);
    float4 o = make_float4(acc.x * inv, acc.y * inv, acc.z * inv, acc.w * inv);
    *(float4*)(agg + (size_t)n * 128 + l * 4) = o;   // == [n][q*32 + kk]
  }
}

// out1 = relu(agg @ W1_head + b1), emitted as fp16 for the MFMA gemm
__global__ __launch_bounds__(256) void gemm_head1(const float* __restrict__ agg,
                                                  const float* __restrict__ W,
                                                  const float* __restrict__ b,
                                                  _Float16* __restrict__ A16) {
  __shared__ float As[32][68];
  __shared__ float Bs[32][64];
  const int row0 = blockIdx.x * 64;
  const int q = blockIdx.y;
  const int col0 = q * 64;
  const int t = threadIdx.x, tx = t & 15, ty = t >> 4;
  #pragma unroll
  for (int i = 0; i < 2; ++i) {
    int idx = t + i * 256;
    int r = idx >> 3, k4 = idx & 7;
    int rr = row0 + r;
    float4 a = make_float4(0.f, 0.f, 0.f, 0.f);
    if (rr < N_NODES) a = *(const float4*)(agg + (size_t)rr * 128 + q * 32 + k4 * 4);
    As[k4 * 4 + 0][r] = a.x;
    As[k4 * 4 + 1][r] = a.y;
    As[k4 * 4 + 2][r] = a.z;
    As[k4 * 4 + 3][r] = a.w;
  }
  #pragma unroll
  for (int i = 0; i < 2; ++i) {
    int idx = t + i * 256;
    int k = idx >> 4, c4 = idx & 15;
    *(float4*)&Bs[k][c4 * 4] = *(const float4*)(W + (size_t)k * D + col0 + c4 * 4);
  }
  __syncthreads();
  float acc[4][4] = {{0.f}};
  #pragma unroll
  for (int k = 0; k < 32; ++k) {
    float4 av = *(const float4*)&As[k][ty * 4];
    float4 bv = *(const float4*)&Bs[k][tx * 4];
    acc[0][0] += av.x * bv.x; acc[0][1] += av.x * bv.y;
    acc[0][2] += av.x * bv.z; acc[0][3] += av.x * bv.w;
    acc[1][0] += av.y * bv.x; acc[1][1] += av.y * bv.y;
    acc[1][2] += av.y * bv.z; acc[1][3] += av.y * bv.w;
    acc[2][0] += av.z * bv.x; acc[2][1] += av.z * bv.y;
    acc[2][2] += av.z * bv.z; acc[2][3] += av.z * bv.w;
    acc[3][0] += av.w * bv.x; acc[3][1] += av.w * bv.y;
    acc[3][2] += av.w * bv.z; acc[3][3] += av.w * bv.w;
  }
  float4 bv = *(const float4*)(b + col0 + tx * 4);
  const float bb[4] = {bv.x, bv.y, bv.z, bv.w};
  #pragma unroll
  for (int i = 0; i < 4; ++i) {
    int rr = row0 + ty * 4 + i;
    if (rr < N_NODES) {
      h16x4 o4;
      #pragma unroll
      for (int j = 0; j < 4; ++j)
        o4[j] = (_Float16)fmaxf(acc[i][j] + bb[j], 0.f);
      *(h16x4*)(A16 + (size_t)rr * D + col0 + tx * 4) = o4;
    }
  }
}

// ===== layer-2 GEMM via fp16 MFMA (single product); h2 out fp16, logits fp32 =====
__global__ __launch_bounds__(256) void gemm2_mfma(
    const _Float16* __restrict__ A16, const _Float16* __restrict__ Wt,
    const float* __restrict__ asrc, const float* __restrict__ adst,
    _Float16* __restrict__ h2, float* __restrict__ alps, float* __restrict__ alpd) {
  __shared__ __attribute__((aligned(16))) _Float16 As[128][40];
  __shared__ __attribute__((aligned(16))) _Float16 Bs[128][40];
  const int row0 = blockIdx.x * 128;
  const int col0 = blockIdx.y * 128;
  const int t = threadIdx.x;
  const int wave = t >> 6, lane = t & 63;
  const int wr = wave >> 1, wc = wave & 1;
  const int lg = lane >> 4, li = lane & 15;

  f32x4 acc[4][4];
  #pragma unroll
  for (int m = 0; m < 4; ++m)
    #pragma unroll
    for (int n = 0; n < 4; ++n) acc[m][n] = (f32x4)0.f;

  for (int kc = 0; kc < D; kc += 32) {
    #pragma unroll
    for (int i = 0; i < 2; ++i) {
      int idx = t + i * 256;          // 0..511
      int r = idx >> 2, seg = idx & 3;
      int rr = row0 + r;
      uint4 va = make_uint4(0, 0, 0, 0);
      if (rr < N_NODES) va = *(const uint4*)(A16 + (size_t)rr * D + kc + seg * 8);
      *(uint4*)&As[r][seg * 8] = va;
      uint4 vb = *(const uint4*)(Wt + (size_t)(col0 + r) * D + kc + seg * 8);
      *(uint4*)&Bs[r][seg * 8] = vb;
    }
    __syncthreads();
    h16x8 af[4], bf[4];
    #pragma unroll
    for (int m = 0; m < 4; ++m)
      af[m] = *(const h16x8*)&As[wr * 64 + m * 16 + li][lg * 8];
    #pragma unroll
    for (int n = 0; n < 4; ++n)
      bf[n] = *(const h16x8*)&Bs[wc * 64 + n * 16 + li][lg * 8];
    #pragma unroll
    for (int m = 0; m < 4; ++m)
      #pragma unroll
      for (int n = 0; n < 4; ++n)
        acc[m][n] = __builtin_amdgcn_mfma_f32_16x16x32_f16(af[m], bf[n], acc[m][n], 0, 0, 0);
    __syncthreads();
  }

  // store h2 tile as fp16
  #pragma unroll
  for (int m = 0; m < 4; ++m) {
    #pragma unroll
    for (int reg = 0; reg < 4; ++reg) {
      int rr = row0 + wr * 64 + m * 16 + lg * 4 + reg;
      if (rr < N_NODES) {
        #pragma unroll
        for (int n = 0; n < 4; ++n)
          h2[(size_t)rr * D + col0 + wc * 64 + n * 16 + li] = (_Float16)acc[m][n][reg];
      }
    }
  }

  // fused attention logits (fp32 accumulators): this wave's 64 cols == head q
  const int q = blockIdx.y * 2 + wc;
  float wsv[4], wdv[4];
  #pragma unroll
  for (int n = 0; n < 4; ++n) {
    wsv[n] = asrc[q * HID + n * 16 + li];
    wdv[n] = adst[q * HID + n * 16 + li];
  }
  #pragma unroll
  for (int m = 0; m < 4; ++m) {
    #pragma unroll
    for (int reg = 0; reg < 4; ++reg) {
      float ps = acc[m][0][reg] * wsv[0] + acc[m][1][reg] * wsv[1]
               + acc[m][2][reg] * wsv[2] + acc[m][3][reg] * wsv[3];
      float pd = acc[m][0][reg] * wdv[0] + acc[m][1][reg] * wdv[1]
               + acc[m][2][reg] * wdv[2] + acc[m][3][reg] * wdv[3];
      #pragma unroll
      for (int off = 1; off < 16; off <<= 1) {
        ps += __shfl_xor(ps, off);
        pd += __shfl_xor(pd, off);
      }
      int rr = row0 + wr * 64 + m * 16 + lg * 4 + reg;
      if (li == 0 && rr < N_NODES) {
        alps[rr * HEADS + q] = ps * LOG2E;
        alpd[rr * HEADS + q] = pd * LOG2E;
      }
    }
  }
}

// ====== layer-2 gather: 2 nodes/wave, 8 ch/lane, NO online max, 6-edge batch,
//        fused pair-head GEMV ======
__global__ __launch_bounds__(256) void gat_gather2_k(
    const int* __restrict__ rowptr, const int* __restrict__ csr,
    const float* __restrict__ alps, const float* __restrict__ alpd,
    const _Float16* __restrict__ h, const float* __restrict__ b,
    const float* __restrict__ hw,
    float* __restrict__ u, float* __restrict__ v) {
  int wid2 = (blockIdx.x * 256 + threadIdx.x) >> 6;
  int lane = threadIdx.x & 63;
  int half = lane >> 5, l = lane & 31;
  int n = wid2 * 2 + half;
  bool valid = n < N_NODES;
  int q = l >> 3;                      // head of my 8 channels
  int beg = valid ? rowptr[n] : 0;
  int end = valid ? rowptr[n + 1] : 0;
  float ad = valid ? alpd[n * HEADS + q] : 0.f;

  float den = 0.f;
  float acc[8] = {0.f, 0.f, 0.f, 0.f, 0.f, 0.f, 0.f, 0.f};

  for (int i = beg; i < end; i += 6) {
    int s[6]; bool ok[6]; float xl[6]; h16x8 hv[6];
    #pragma unroll
    for (int j = 0; j < 6; ++j) { ok[j] = (i + j) < end; s[j] = ok[j] ? csr[i + j] : 0; }
    #pragma unroll
    for (int j = 0; j < 6; ++j) xl[j] = alps[s[j] * HEADS + q];
    #pragma unroll
    for (int j = 0; j < 6; ++j) hv[j] = *(const h16x8*)(h + (size_t)s[j] * D + l * 8);
    float e[6];
    #pragma unroll
    for (int j = 0; j < 6; ++j) {
      float t = xl[j] + ad;
      t = fmaxf(t, NEG_SLOPE * t);
      e[j] = ok[j] ? ex2(t) : 0.f;
    }
    den += ((e[0] + e[1]) + (e[2] + e[3])) + (e[4] + e[5]);
    #pragma unroll
    for (int ch = 0; ch < 8; ++ch) {
      float a = acc[ch];
      a = fmaf((float)hv[0][ch], e[0], a);
      a = fmaf((float)hv[1][ch], e[1], a);
      a = fmaf((float)hv[2][ch], e[2], a);
      a = fmaf((float)hv[3][ch], e[3], a);
      a = fmaf((float)hv[4][ch], e[4], a);
      a = fmaf((float)hv[5][ch], e[5], a);
      acc[ch] = a;
    }
  }

  float inv = 1.f / (den + 1e-16f);
  float4 b0 = *(const float4*)(b + l * 8);
  float4 b1 = *(const float4*)(b + l * 8 + 4);
  float4 w00 = *(const float4*)(hw + l * 8);
  float4 w01 = *(const float4*)(hw + l * 8 + 4);
  float4 w10 = *(const float4*)(hw + D + l * 8);
  float4 w11 = *(const float4*)(hw + D + l * 8 + 4);
  const float* bb[2] = {(const float*)&b0, (const float*)&b1};
  const float* w0p[2] = {(const float*)&w00, (const float*)&w01};
  const float* w1p[2] = {(const float*)&w10, (const float*)&w11};
  float su = 0.f, sv = 0.f;
  #pragma unroll
  for (int ch = 0; ch < 8; ++ch) {
    float o = fmaxf(acc[ch] * inv + bb[ch >> 2][ch & 3], 0.f);
    su = fmaf(o, w0p[ch >> 2][ch & 3], su);
    sv = fmaf(o, w1p[ch >> 2][ch & 3], sv);
  }
  #pragma unroll
  for (int off = 16; off; off >>= 1) {    // xor masks <32 stay within the half
    su += __shfl_xor(su, off);
    sv += __shfl_xor(sv, off);
  }
  if (l == 0 && valid) { u[n] = su; v[n] = sv; }
}

// ---- pair lookup: out[p] = u[a] + v[b] + hb ----
__global__ void pair_lu_k(const int* __restrict__ pairs,
                          const float* __restrict__ u, const float* __restrict__ v,
                          const float* __restrict__ hb, float* __restrict__ out) {
  int g = blockIdx.x * 256 + threadIdx.x;
  if (g >= P_PAIRS) return;
  int a = pairs[g * 2], b = pairs[g * 2 + 1];
  out[g] = u[a] + v[b] + hb[0];
}

extern "C" void kernel_launch(void* const* d_in, const int* in_sizes, int n_in,
                              void* d_out, int out_size, void* d_ws, size_t ws_size,
                              hipStream_t stream) {
  const float* x    = (const float*)d_in[0];
  const int*   ei   = (const int*)d_in[1];
  const int*   prs  = (const int*)d_in[2];
  const float* W1   = (const float*)d_in[3];
  const float* as1  = (const float*)d_in[4];
  const float* ad1  = (const float*)d_in[5];
  const float* b1   = (const float*)d_in[6];
  const float* W2   = (const float*)d_in[7];
  const float* as2  = (const float*)d_in[8];
  const float* ad2  = (const float*)d_in[9];
  const float* b2   = (const float*)d_in[10];
  const float* hw   = (const float*)d_in[11];
  const float* hb   = (const float*)d_in[12];
  float* out = (float*)d_out;

  const int NPAD = 50048;   // 391*128

  char* w = (char*)d_ws;
  float* buf0 = (float*)w;             w += (size_t)N_NODES * D * 4;     // agg1 [n][128] / h2 fp16 [n][256]
  float* alps = (float*)w;             w += (size_t)N_NODES * HEADS * 4;
  float* alpd = (float*)w;             w += (size_t)N_NODES * HEADS * 4;
  int* rowptr = (int*)w;               w += (size_t)(N_NODES + 1) * 4;
  int* csr    = (int*)w;               w += (size_t)E_TOT * 4;
  float* uu   = (float*)w;             w += (size_t)N_NODES * 4;
  float* vv   = (float*)w;             w += (size_t)N_NODES * 4;
  float* wa_s = (float*)w;             w += 128 * 4;
  float* wa_d = (float*)w;             w += 128 * 4;
  _Float16* A16 = (_Float16*)w;        w += (size_t)NPAD * D * 2;        // out1 fp16
  _Float16* Wt  = (_Float16*)w;        w += (size_t)D * D * 2;           // W2T fp16

  _Float16* h2f16 = (_Float16*)buf0;

  // CSR-build temporaries aliased into buf0 (first real write to buf0 is
  // gat_gather1_k, which runs strictly after scatter_k on this stream)
  int* deg      = (int*)buf0;
  int* pos      = deg + N_NODES;
  int* scan_out = pos + N_NODES;
  int* bsum     = scan_out + N_NODES;

  const int eBlk     = (E_TOT + 255) / 256;               // 3321
  const int nScanBlk = (N_NODES + SCAN_BS - 1) / SCAN_BS; // 49
  const int nBlk256  = (N_NODES + 255) / 256;             // 196
  const int a1Blk    = (N_NODES * 8 + 255) / 256;         // 1563
  const int g1Blk    = ((N_NODES + 1) / 2 * 64 + 255) / 256; // 6250 (2 nodes/wave)
  const int pairBlk  = (P_PAIRS + 255) / 256;             // 782
  const dim3 headGrid((N_NODES + 63) / 64, HEADS);        // 782 x 4 (K=32 GEMM)
  const dim3 mfmaGrid(NPAD / 128, D / 128);               // 391 x 2

  // ---------- CSR build (once, reused by both layers) ----------
  hipMemsetAsync(deg, 0, (size_t)2 * N_NODES * 4, stream);  // deg + pos in one memset
  count_k<<<eBlk, 256, 0, stream>>>(ei, deg);
  scan_block_k<<<nScanBlk, SCAN_BS, 0, stream>>>(deg, scan_out, bsum, N_NODES);
  scan_top_k<<<1, 256, 0, stream>>>(bsum, nScanBlk);
  add_off_k<<<nBlk256, 256, 0, stream>>>(scan_out, bsum, rowptr);
  scatter_k<<<eBlk, 256, 0, stream>>>(ei, rowptr, pos, csr);

  // ---------- weight prep ----------
  prep_wa1_k<<<1, 256, 0, stream>>>(W1, as1, ad1, wa_s, wa_d);
  prep_w2t_k<<<D * D / 256, 256, 0, stream>>>(W2, Wt);

  // ---------- layer 1 (x-space aggregation) ----------
  alphas1_k<<<a1Blk, 256, 0, stream>>>(x, wa_s, wa_d, alps, alpd);
  gat_gather1_k<<<g1Blk, 256, 0, stream>>>(rowptr, csr, alps, alpd, x, buf0);
  gemm_head1<<<headGrid, 256, 0, stream>>>(buf0, W1, b1, A16);

  // ---------- layer 2 (fp16 MFMA GEMM + fp16 gather w/ fused pair head) ----------
  gemm2_mfma<<<mfmaGrid, 256, 0, stream>>>(A16, Wt, as2, ad2, h2f16, alps, alpd);
  gat_gather2_k<<<g1Blk, 256, 0, stream>>>(rowptr, csr, alps, alpd, h2f16, b2, hw, uu, vv);

  // ---------- pair head ----------
  pair_lu_k<<<pairBlk, 256, 0, stream>>>(prs, uu, vv, hb, out);
}

// Round 14
// 320.456 us; speedup vs baseline: 1.2230x; 1.0853x over previous
//
#include <hip/hip_runtime.h>

#define N_NODES 50000
#define E_EDGES 800000
#define E_TOT   (E_EDGES + N_NODES)   // edges + self loops
#define P_PAIRS 200000
#define IN_DIM  32
#define HID     64
#define HEADS   4
#define D       256
#define NEG_SLOPE 0.2f
#define SCAN_BS 1024
#define LOG2E 1.4426950408889634f

typedef float    f32x4 __attribute__((ext_vector_type(4)));
typedef _Float16 h16x8 __attribute__((ext_vector_type(8)));
typedef _Float16 h16x4 __attribute__((ext_vector_type(4)));

__device__ __forceinline__ float ex2(float v) { return __builtin_amdgcn_exp2f(v); }

__device__ __forceinline__ void edge_sd(const int* __restrict__ ei, int e, int& s, int& d) {
  if (e < E_EDGES) { s = ei[e]; d = ei[E_EDGES + e]; }
  else             { s = d = e - E_EDGES; }
}

// ================= CSR build (dst-grouped), rank-based scatter =================
__global__ void count_k(const int* __restrict__ ei, int* __restrict__ deg,
                        int* __restrict__ rank) {
  int e = blockIdx.x * 256 + threadIdx.x;
  if (e >= E_TOT) return;
  int s, d; edge_sd(ei, e, s, d);
  rank[e] = atomicAdd(&deg[d], 1);
}

__global__ __launch_bounds__(SCAN_BS) void scan_block_k(const int* __restrict__ in,
                                                        int* __restrict__ out,
                                                        int* __restrict__ bsum, int n) {
  __shared__ int tmp[SCAN_BS];
  int g = blockIdx.x * SCAN_BS + threadIdx.x;
  tmp[threadIdx.x] = (g < n) ? in[g] : 0;
  __syncthreads();
  for (int off = 1; off < SCAN_BS; off <<= 1) {
    int t = 0;
    if ((int)threadIdx.x >= off) t = tmp[threadIdx.x - off];
    __syncthreads();
    if ((int)threadIdx.x >= off) tmp[threadIdx.x] += t;
    __syncthreads();
  }
  if (g < n) out[g] = tmp[threadIdx.x];
  if (threadIdx.x == SCAN_BS - 1) bsum[blockIdx.x] = tmp[SCAN_BS - 1];
}

__global__ void scan_top_k(int* __restrict__ bsum, int nb) {
  __shared__ int tmp[256];
  tmp[threadIdx.x] = ((int)threadIdx.x < nb) ? bsum[threadIdx.x] : 0;
  __syncthreads();
  for (int off = 1; off < 256; off <<= 1) {
    int t = 0;
    if ((int)threadIdx.x >= off) t = tmp[threadIdx.x - off];
    __syncthreads();
    if ((int)threadIdx.x >= off) tmp[threadIdx.x] += t;
    __syncthreads();
  }
  if ((int)threadIdx.x < nb) bsum[threadIdx.x] = tmp[threadIdx.x];
}

__global__ void add_off_k(const int* __restrict__ scan_out,
                          const int* __restrict__ bsum,
                          int* __restrict__ rowptr) {
  int g = blockIdx.x * 256 + threadIdx.x;
  if (g >= N_NODES) return;
  int blk = g / SCAN_BS;
  int add = blk ? bsum[blk - 1] : 0;
  rowptr[g + 1] = scan_out[g] + add;
  if (g == 0) rowptr[0] = 0;
}

// no atomic: slot was pre-assigned by count_k's rank
__global__ void scatter_k(const int* __restrict__ ei,
                          const int* __restrict__ rowptr,
                          const int* __restrict__ rank, int* __restrict__ csr) {
  int e = blockIdx.x * 256 + threadIdx.x;
  if (e >= E_TOT) return;
  int s, d; edge_sd(ei, e, s, d);
  csr[rowptr[d] + rank[e]] = s;
}

// ================ fused weight prep ================
// 256 blocks: all do W2T fp16; block 0 additionally computes wa1 (W1 @ att1).
__global__ void prep_k(const float* __restrict__ W1,
                       const float* __restrict__ as1,
                       const float* __restrict__ ad1,
                       const float* __restrict__ W2,
                       float* __restrict__ wa_s, float* __restrict__ wa_d,
                       _Float16* __restrict__ Wt) {
  int g = blockIdx.x * 256 + threadIdx.x;   // 65536
  int col = g >> 8, k = g & 255;
  Wt[g] = (_Float16)W2[(size_t)k * D + col];
  if (blockIdx.x == 0) {
    int t = threadIdx.x;
    int kk = (t >> 2) & 31, h = t & 3;
    const float* att = (t < 128) ? as1 : ad1;
    float sum = 0.f;
    for (int c = 0; c < HID; ++c) sum += W1[kk * D + h * HID + c] * att[h * HID + c];
    float* dst = (t < 128) ? wa_s : wa_d;
    dst[kk * 4 + h] = sum * LOG2E;
  }
}

// alps1[n,h] = x[n] . wa_s[:,h] ; 8 lanes per node, 8 nodes per wave
__global__ __launch_bounds__(256) void alphas1_k(const float* __restrict__ x,
                                                 const float* __restrict__ wa_s,
                                                 const float* __restrict__ wa_d,
                                                 float* __restrict__ alps,
                                                 float* __restrict__ alpd) {
  int w = (blockIdx.x * 256 + threadIdx.x) >> 6;
  int lane = threadIdx.x & 63;
  int n = w * 8 + (lane >> 3);
  int j = lane & 7;
  float4 xv = make_float4(0.f, 0.f, 0.f, 0.f);
  if (n < N_NODES) xv = *(const float4*)(x + (size_t)n * IN_DIM + j * 4);
  float ps[4] = {0.f, 0.f, 0.f, 0.f}, pd[4] = {0.f, 0.f, 0.f, 0.f};
  #pragma unroll
  for (int kk = 0; kk < 4; ++kk) {
    float xk = ((const float*)&xv)[kk];
    float4 ws = *(const float4*)(wa_s + (j * 4 + kk) * 4);
    float4 wd = *(const float4*)(wa_d + (j * 4 + kk) * 4);
    ps[0] += xk * ws.x; ps[1] += xk * ws.y; ps[2] += xk * ws.z; ps[3] += xk * ws.w;
    pd[0] += xk * wd.x; pd[1] += xk * wd.y; pd[2] += xk * wd.z; pd[3] += xk * wd.w;
  }
  #pragma unroll
  for (int off = 1; off < 8; off <<= 1) {
    #pragma unroll
    for (int h = 0; h < 4; ++h) {
      ps[h] += __shfl_xor(ps[h], off);
      pd[h] += __shfl_xor(pd[h], off);
    }
  }
  if (j == 0 && n < N_NODES) {
    *(float4*)(alps + n * 4) = make_float4(ps[0], ps[1], ps[2], ps[3]);
    *(float4*)(alpd + n * 4) = make_float4(pd[0], pd[1], pd[2], pd[3]);
  }
}

// x-space gather: half-wave per node; lane l owns head q=l>>3, channels kk=(l&7)*4.
// No online max (bounded logits). 8-edge batches for MLP.
__global__ __launch_bounds__(256) void gat_gather1_k(
    const int* __restrict__ rowptr, const int* __restrict__ csr,
    const float* __restrict__ alps, const float* __restrict__ alpd,
    const float* __restrict__ x, float* __restrict__ agg) {
  int wid2 = (blockIdx.x * 256 + threadIdx.x) >> 6;
  int lane = threadIdx.x & 63;
  int half = lane >> 5, l = lane & 31;
  int n = wid2 * 2 + half;
  bool valid = n < N_NODES;
  int q = l >> 3;                       // my head
  int kk = (l & 7) * 4;                 // my x-channel base
  int beg = valid ? rowptr[n] : 0;
  int end = valid ? rowptr[n + 1] : 0;
  float ad = valid ? alpd[n * HEADS + q] : 0.f;

  float den = 0.f;
  float4 acc = make_float4(0.f, 0.f, 0.f, 0.f);

  for (int i = beg; i < end; i += 8) {
    int s[8]; bool ok[8]; float xl[8]; float4 xv[8];
    #pragma unroll
    for (int j = 0; j < 8; ++j) { ok[j] = (i + j) < end; s[j] = ok[j] ? csr[i + j] : 0; }
    #pragma unroll
    for (int j = 0; j < 8; ++j) xl[j] = alps[s[j] * HEADS + q];
    #pragma unroll
    for (int j = 0; j < 8; ++j) xv[j] = *(const float4*)(x + (size_t)s[j] * IN_DIM + kk);
    float e[8];
    #pragma unroll
    for (int j = 0; j < 8; ++j) {
      float t = xl[j] + ad;
      t = fmaxf(t, NEG_SLOPE * t);
      e[j] = ok[j] ? ex2(t) : 0.f;
    }
    den += (((e[0] + e[1]) + (e[2] + e[3])) + ((e[4] + e[5]) + (e[6] + e[7])));
    #pragma unroll
    for (int j = 0; j < 8; ++j) {
      acc.x = fmaf(e[j], xv[j].x, acc.x);
      acc.y = fmaf(e[j], xv[j].y, acc.y);
      acc.z = fmaf(e[j], xv[j].z, acc.z);
      acc.w = fmaf(e[j], xv[j].w, acc.w);
    }
  }
  if (valid) {
    float inv = 1.f / (den + 1e-16f);
    float4 o = make_float4(acc.x * inv, acc.y * inv, acc.z * inv, acc.w * inv);
    *(float4*)(agg + (size_t)n * 128 + l * 4) = o;   // == [n][q*32 + kk]
  }
}

// out1 = relu(agg @ W1_head + b1), emitted as fp16 for the MFMA gemm
__global__ __launch_bounds__(256) void gemm_head1(const float* __restrict__ agg,
                                                  const float* __restrict__ W,
                                                  const float* __restrict__ b,
                                                  _Float16* __restrict__ A16) {
  __shared__ float As[32][68];
  __shared__ float Bs[32][64];
  const int row0 = blockIdx.x * 64;
  const int q = blockIdx.y;
  const int col0 = q * 64;
  const int t = threadIdx.x, tx = t & 15, ty = t >> 4;
  #pragma unroll
  for (int i = 0; i < 2; ++i) {
    int idx = t + i * 256;
    int r = idx >> 3, k4 = idx & 7;
    int rr = row0 + r;
    float4 a = make_float4(0.f, 0.f, 0.f, 0.f);
    if (rr < N_NODES) a = *(const float4*)(agg + (size_t)rr * 128 + q * 32 + k4 * 4);
    As[k4 * 4 + 0][r] = a.x;
    As[k4 * 4 + 1][r] = a.y;
    As[k4 * 4 + 2][r] = a.z;
    As[k4 * 4 + 3][r] = a.w;
  }
  #pragma unroll
  for (int i = 0; i < 2; ++i) {
    int idx = t + i * 256;
    int k = idx >> 4, c4 = idx & 15;
    *(float4*)&Bs[k][c4 * 4] = *(const float4*)(W + (size_t)k * D + col0 + c4 * 4);
  }
  __syncthreads();
  float acc[4][4] = {{0.f}};
  #pragma unroll
  for (int k = 0; k < 32; ++k) {
    float4 av = *(const float4*)&As[k][ty * 4];
    float4 bv = *(const float4*)&Bs[k][tx * 4];
    acc[0][0] += av.x * bv.x; acc[0][1] += av.x * bv.y;
    acc[0][2] += av.x * bv.z; acc[0][3] += av.x * bv.w;
    acc[1][0] += av.y * bv.x; acc[1][1] += av.y * bv.y;
    acc[1][2] += av.y * bv.z; acc[1][3] += av.y * bv.w;
    acc[2][0] += av.z * bv.x; acc[2][1] += av.z * bv.y;
    acc[2][2] += av.z * bv.z; acc[2][3] += av.z * bv.w;
    acc[3][0] += av.w * bv.x; acc[3][1] += av.w * bv.y;
    acc[3][2] += av.w * bv.z; acc[3][3] += av.w * bv.w;
  }
  float4 bv = *(const float4*)(b + col0 + tx * 4);
  const float bb[4] = {bv.x, bv.y, bv.z, bv.w};
  #pragma unroll
  for (int i = 0; i < 4; ++i) {
    int rr = row0 + ty * 4 + i;
    if (rr < N_NODES) {
      h16x4 o4;
      #pragma unroll
      for (int j = 0; j < 4; ++j)
        o4[j] = (_Float16)fmaxf(acc[i][j] + bb[j], 0.f);
      *(h16x4*)(A16 + (size_t)rr * D + col0 + tx * 4) = o4;
    }
  }
}

// ===== layer-2 GEMM via fp16 MFMA (single product); h2 out fp16, logits fp32 =====
__global__ __launch_bounds__(256) void gemm2_mfma(
    const _Float16* __restrict__ A16, const _Float16* __restrict__ Wt,
    const float* __restrict__ asrc, const float* __restrict__ adst,
    _Float16* __restrict__ h2, float* __restrict__ alps, float* __restrict__ alpd) {
  __shared__ __attribute__((aligned(16))) _Float16 As[128][40];
  __shared__ __attribute__((aligned(16))) _Float16 Bs[128][40];
  const int row0 = blockIdx.x * 128;
  const int col0 = blockIdx.y * 128;
  const int t = threadIdx.x;
  const int wave = t >> 6, lane = t & 63;
  const int wr = wave >> 1, wc = wave & 1;
  const int lg = lane >> 4, li = lane & 15;

  f32x4 acc[4][4];
  #pragma unroll
  for (int m = 0; m < 4; ++m)
    #pragma unroll
    for (int n = 0; n < 4; ++n) acc[m][n] = (f32x4)0.f;

  for (int kc = 0; kc < D; kc += 32) {
    #pragma unroll
    for (int i = 0; i < 2; ++i) {
      int idx = t + i * 256;          // 0..511
      int r = idx >> 2, seg = idx & 3;
      int rr = row0 + r;
      uint4 va = make_uint4(0, 0, 0, 0);
      if (rr < N_NODES) va = *(const uint4*)(A16 + (size_t)rr * D + kc + seg * 8);
      *(uint4*)&As[r][seg * 8] = va;
      uint4 vb = *(const uint4*)(Wt + (size_t)(col0 + r) * D + kc + seg * 8);
      *(uint4*)&Bs[r][seg * 8] = vb;
    }
    __syncthreads();
    h16x8 af[4], bf[4];
    #pragma unroll
    for (int m = 0; m < 4; ++m)
      af[m] = *(const h16x8*)&As[wr * 64 + m * 16 + li][lg * 8];
    #pragma unroll
    for (int n = 0; n < 4; ++n)
      bf[n] = *(const h16x8*)&Bs[wc * 64 + n * 16 + li][lg * 8];
    #pragma unroll
    for (int m = 0; m < 4; ++m)
      #pragma unroll
      for (int n = 0; n < 4; ++n)
        acc[m][n] = __builtin_amdgcn_mfma_f32_16x16x32_f16(af[m], bf[n], acc[m][n], 0, 0, 0);
    __syncthreads();
  }

  // store h2 tile as fp16
  #pragma unroll
  for (int m = 0; m < 4; ++m) {
    #pragma unroll
    for (int reg = 0; reg < 4; ++reg) {
      int rr = row0 + wr * 64 + m * 16 + lg * 4 + reg;
      if (rr < N_NODES) {
        #pragma unroll
        for (int n = 0; n < 4; ++n)
          h2[(size_t)rr * D + col0 + wc * 64 + n * 16 + li] = (_Float16)acc[m][n][reg];
      }
    }
  }

  // fused attention logits (fp32 accumulators): this wave's 64 cols == head q
  const int q = blockIdx.y * 2 + wc;
  float wsv[4], wdv[4];
  #pragma unroll
  for (int n = 0; n < 4; ++n) {
    wsv[n] = asrc[q * HID + n * 16 + li];
    wdv[n] = adst[q * HID + n * 16 + li];
  }
  #pragma unroll
  for (int m = 0; m < 4; ++m) {
    #pragma unroll
    for (int reg = 0; reg < 4; ++reg) {
      float ps = acc[m][0][reg] * wsv[0] + acc[m][1][reg] * wsv[1]
               + acc[m][2][reg] * wsv[2] + acc[m][3][reg] * wsv[3];
      float pd = acc[m][0][reg] * wdv[0] + acc[m][1][reg] * wdv[1]
               + acc[m][2][reg] * wdv[2] + acc[m][3][reg] * wdv[3];
      #pragma unroll
      for (int off = 1; off < 16; off <<= 1) {
        ps += __shfl_xor(ps, off);
        pd += __shfl_xor(pd, off);
      }
      int rr = row0 + wr * 64 + m * 16 + lg * 4 + reg;
      if (li == 0 && rr < N_NODES) {
        alps[rr * HEADS + q] = ps * LOG2E;
        alpd[rr * HEADS + q] = pd * LOG2E;
      }
    }
  }
}

// ====== layer-2 gather: 2 nodes/wave, 8 ch/lane, NO online max, 8-edge batch,
//        fused pair-head GEMV ======
__global__ __launch_bounds__(256) void gat_gather2_k(
    const int* __restrict__ rowptr, const int* __restrict__ csr,
    const float* __restrict__ alps, const float* __restrict__ alpd,
    const _Float16* __restrict__ h, const float* __restrict__ b,
    const float* __restrict__ hw,
    float* __restrict__ u, float* __restrict__ v) {
  int wid2 = (blockIdx.x * 256 + threadIdx.x) >> 6;
  int lane = threadIdx.x & 63;
  int half = lane >> 5, l = lane & 31;
  int n = wid2 * 2 + half;
  bool valid = n < N_NODES;
  int q = l >> 3;                      // head of my 8 channels
  int beg = valid ? rowptr[n] : 0;
  int end = valid ? rowptr[n + 1] : 0;
  float ad = valid ? alpd[n * HEADS + q] : 0.f;

  float den = 0.f;
  float acc[8] = {0.f, 0.f, 0.f, 0.f, 0.f, 0.f, 0.f, 0.f};

  for (int i = beg; i < end; i += 8) {
    int s[8]; bool ok[8]; float xl[8]; h16x8 hv[8];
    #pragma unroll
    for (int j = 0; j < 8; ++j) { ok[j] = (i + j) < end; s[j] = ok[j] ? csr[i + j] : 0; }
    #pragma unroll
    for (int j = 0; j < 8; ++j) xl[j] = alps[s[j] * HEADS + q];
    #pragma unroll
    for (int j = 0; j < 8; ++j) hv[j] = *(const h16x8*)(h + (size_t)s[j] * D + l * 8);
    float e[8];
    #pragma unroll
    for (int j = 0; j < 8; ++j) {
      float t = xl[j] + ad;
      t = fmaxf(t, NEG_SLOPE * t);
      e[j] = ok[j] ? ex2(t) : 0.f;
    }
    den += (((e[0] + e[1]) + (e[2] + e[3])) + ((e[4] + e[5]) + (e[6] + e[7])));
    #pragma unroll
    for (int ch = 0; ch < 8; ++ch) {
      float a = acc[ch];
      #pragma unroll
      for (int j = 0; j < 8; ++j)
        a = fmaf((float)hv[j][ch], e[j], a);
      acc[ch] = a;
    }
  }

  float inv = 1.f / (den + 1e-16f);
  float4 b0 = *(const float4*)(b + l * 8);
  float4 b1 = *(const float4*)(b + l * 8 + 4);
  float4 w00 = *(const float4*)(hw + l * 8);
  float4 w01 = *(const float4*)(hw + l * 8 + 4);
  float4 w10 = *(const float4*)(hw + D + l * 8);
  float4 w11 = *(const float4*)(hw + D + l * 8 + 4);
  const float* bb[2] = {(const float*)&b0, (const float*)&b1};
  const float* w0p[2] = {(const float*)&w00, (const float*)&w01};
  const float* w1p[2] = {(const float*)&w10, (const float*)&w11};
  float su = 0.f, sv = 0.f;
  #pragma unroll
  for (int ch = 0; ch < 8; ++ch) {
    float o = fmaxf(acc[ch] * inv + bb[ch >> 2][ch & 3], 0.f);
    su = fmaf(o, w0p[ch >> 2][ch & 3], su);
    sv = fmaf(o, w1p[ch >> 2][ch & 3], sv);
  }
  #pragma unroll
  for (int off = 16; off; off >>= 1) {    // xor masks <32 stay within the half
    su += __shfl_xor(su, off);
    sv += __shfl_xor(sv, off);
  }
  if (l == 0 && valid) { u[n] = su; v[n] = sv; }
}

// ---- pair lookup: out[p] = u[a] + v[b] + hb ----
__global__ void pair_lu_k(const int* __restrict__ pairs,
                          const float* __restrict__ u, const float* __restrict__ v,
                          const float* __restrict__ hb, float* __restrict__ out) {
  int g = blockIdx.x * 256 + threadIdx.x;
  if (g >= P_PAIRS) return;
  int a = pairs[g * 2], b = pairs[g * 2 + 1];
  out[g] = u[a] + v[b] + hb[0];
}

extern "C" void kernel_launch(void* const* d_in, const int* in_sizes, int n_in,
                              void* d_out, int out_size, void* d_ws, size_t ws_size,
                              hipStream_t stream) {
  const float* x    = (const float*)d_in[0];
  const int*   ei   = (const int*)d_in[1];
  const int*   prs  = (const int*)d_in[2];
  const float* W1   = (const float*)d_in[3];
  const float* as1  = (const float*)d_in[4];
  const float* ad1  = (const float*)d_in[5];
  const float* b1   = (const float*)d_in[6];
  const float* W2   = (const float*)d_in[7];
  const float* as2  = (const float*)d_in[8];
  const float* ad2  = (const float*)d_in[9];
  const float* b2   = (const float*)d_in[10];
  const float* hw   = (const float*)d_in[11];
  const float* hb   = (const float*)d_in[12];
  float* out = (float*)d_out;

  const int NPAD = 50048;   // 391*128

  char* w = (char*)d_ws;
  float* buf0 = (float*)w;             w += (size_t)N_NODES * D * 4;     // agg1 [n][128] / h2 fp16 [n][256]
  float* alps = (float*)w;             w += (size_t)N_NODES * HEADS * 4;
  float* alpd = (float*)w;             w += (size_t)N_NODES * HEADS * 4;
  int* rowptr = (int*)w;               w += (size_t)(N_NODES + 1) * 4;
  int* csr    = (int*)w;               w += (size_t)E_TOT * 4;
  float* uu   = (float*)w;             w += (size_t)N_NODES * 4;
  float* vv   = (float*)w;             w += (size_t)N_NODES * 4;
  float* wa_s = (float*)w;             w += 128 * 4;
  float* wa_d = (float*)w;             w += 128 * 4;
  _Float16* A16 = (_Float16*)w;        w += (size_t)NPAD * D * 2;        // out1 fp16
  _Float16* Wt  = (_Float16*)w;        w += (size_t)D * D * 2;           // W2T fp16

  _Float16* h2f16 = (_Float16*)buf0;

  // CSR-build temporaries aliased into buf0 (first real write to buf0 is
  // gat_gather1_k, which runs strictly after scatter_k on this stream)
  int* deg      = (int*)buf0;                 // N
  int* scan_out = deg + N_NODES;              // N
  int* bsum     = scan_out + N_NODES;         // 64
  int* rank     = bsum + 64;                  // E_TOT (fits: buf0 is 12.8M ints)

  const int eBlk     = (E_TOT + 255) / 256;               // 3321
  const int nScanBlk = (N_NODES + SCAN_BS - 1) / SCAN_BS; // 49
  const int nBlk256  = (N_NODES + 255) / 256;             // 196
  const int a1Blk    = (N_NODES * 8 + 255) / 256;         // 1563
  const int g1Blk    = ((N_NODES + 1) / 2 * 64 + 255) / 256; // 6250 (2 nodes/wave)
  const int pairBlk  = (P_PAIRS + 255) / 256;             // 782
  const dim3 headGrid((N_NODES + 63) / 64, HEADS);        // 782 x 4 (K=32 GEMM)
  const dim3 mfmaGrid(NPAD / 128, D / 128);               // 391 x 2

  // ---------- CSR build (once, reused by both layers) ----------
  hipMemsetAsync(deg, 0, (size_t)N_NODES * 4, stream);
  count_k<<<eBlk, 256, 0, stream>>>(ei, deg, rank);
  scan_block_k<<<nScanBlk, SCAN_BS, 0, stream>>>(deg, scan_out, bsum, N_NODES);
  scan_top_k<<<1, 256, 0, stream>>>(bsum, nScanBlk);
  add_off_k<<<nBlk256, 256, 0, stream>>>(scan_out, bsum, rowptr);
  scatter_k<<<eBlk, 256, 0, stream>>>(ei, rowptr, rank, csr);

  // ---------- weight prep (fused) ----------
  prep_k<<<D * D / 256, 256, 0, stream>>>(W1, as1, ad1, W2, wa_s, wa_d, Wt);

  // ---------- layer 1 (x-space aggregation) ----------
  alphas1_k<<<a1Blk, 256, 0, stream>>>(x, wa_s, wa_d, alps, alpd);
  gat_gather1_k<<<g1Blk, 256, 0, stream>>>(rowptr, csr, alps, alpd, x, buf0);
  gemm_head1<<<headGrid, 256, 0, stream>>>(buf0, W1, b1, A16);

  // ---------- layer 2 (fp16 MFMA GEMM + fp16 gather w/ fused pair head) ----------
  gemm2_mfma<<<mfmaGrid, 256, 0, stream>>>(A16, Wt, as2, ad2, h2f16, alps, alpd);
  gat_gather2_k<<<g1Blk, 256, 0, stream>>>(rowptr, csr, alps, alpd, h2f16, b2, hw, uu, vv);

  // ---------- pair head ----------
  pair_lu_k<<<pairBlk, 256, 0, stream>>>(prs, uu, vv, hb, out);
}

// Round 15
// 311.229 us; speedup vs baseline: 1.2593x; 1.0296x over previous
//
#include <hip/hip_runtime.h>

#define N_NODES 50000
#define E_EDGES 800000
#define E_TOT   (E_EDGES + N_NODES)   // edges + self loops
#define P_PAIRS 200000
#define IN_DIM  32
#define HID     64
#define HEADS   4
#define D       256
#define NEG_SLOPE 0.2f
#define SCAN_BS 1024
#define LOG2E 1.4426950408889634f

typedef float    f32x4 __attribute__((ext_vector_type(4)));
typedef _Float16 h16x8 __attribute__((ext_vector_type(8)));
typedef _Float16 h16x4 __attribute__((ext_vector_type(4)));

__device__ __forceinline__ float ex2(float v) { return __builtin_amdgcn_exp2f(v); }

__device__ __forceinline__ void edge_sd(const int* __restrict__ ei, int e, int& s, int& d) {
  if (e < E_EDGES) { s = ei[e]; d = ei[E_EDGES + e]; }
  else             { s = d = e - E_EDGES; }
}

// ============ fused: weight prep (blocks 0..255) + edge count (rest) ============
__global__ void count_prep_k(const int* __restrict__ ei, int* __restrict__ deg,
                             int* __restrict__ rank,
                             const float* __restrict__ W1,
                             const float* __restrict__ as1,
                             const float* __restrict__ ad1,
                             const float* __restrict__ W2,
                             float* __restrict__ wa_s, float* __restrict__ wa_d,
                             _Float16* __restrict__ Wt) {
  if (blockIdx.x < 256) {
    // W2T fp16 + (block 0) wa1
    int g = blockIdx.x * 256 + threadIdx.x;   // 65536
    int col = g >> 8, k = g & 255;
    Wt[g] = (_Float16)W2[(size_t)k * D + col];
    if (blockIdx.x == 0) {
      int t = threadIdx.x;
      int kk = (t >> 2) & 31, h = t & 3;
      const float* att = (t < 128) ? as1 : ad1;
      float sum = 0.f;
      for (int c = 0; c < HID; ++c) sum += W1[kk * D + h * HID + c] * att[h * HID + c];
      float* dst = (t < 128) ? wa_s : wa_d;
      dst[kk * 4 + h] = sum * LOG2E;
    }
  } else {
    int e = (blockIdx.x - 256) * 256 + threadIdx.x;
    if (e >= E_TOT) return;
    int s, d; edge_sd(ei, e, s, d);
    rank[e] = atomicAdd(&deg[d], 1);
  }
}

__global__ __launch_bounds__(SCAN_BS) void scan_block_k(const int* __restrict__ in,
                                                        int* __restrict__ out,
                                                        int* __restrict__ bsum, int n) {
  __shared__ int tmp[SCAN_BS];
  int g = blockIdx.x * SCAN_BS + threadIdx.x;
  tmp[threadIdx.x] = (g < n) ? in[g] : 0;
  __syncthreads();
  for (int off = 1; off < SCAN_BS; off <<= 1) {
    int t = 0;
    if ((int)threadIdx.x >= off) t = tmp[threadIdx.x - off];
    __syncthreads();
    if ((int)threadIdx.x >= off) tmp[threadIdx.x] += t;
    __syncthreads();
  }
  if (g < n) out[g] = tmp[threadIdx.x];
  if (threadIdx.x == SCAN_BS - 1) bsum[blockIdx.x] = tmp[SCAN_BS - 1];
}

// add_off with inline top-scan over the (<=49) raw block sums
__global__ void add_off_k(const int* __restrict__ scan_out,
                          const int* __restrict__ bsum,
                          int* __restrict__ rowptr) {
  int g = blockIdx.x * 256 + threadIdx.x;
  if (g >= N_NODES) return;
  int blk = g / SCAN_BS;
  int add = 0;
  for (int b = 0; b < blk; ++b) add += bsum[b];
  rowptr[g + 1] = scan_out[g] + add;
  if (g == 0) rowptr[0] = 0;
}

// ===== fused: alphas1 (blocks 0..a1Blk) + rank-scatter (rest) =====
__global__ __launch_bounds__(256) void scatter_alphas_k(
    const int* __restrict__ ei, const int* __restrict__ rowptr,
    const int* __restrict__ rank, int* __restrict__ csr,
    const float* __restrict__ x,
    const float* __restrict__ wa_s, const float* __restrict__ wa_d,
    float* __restrict__ alps, float* __restrict__ alpd, int a1Blk) {
  if ((int)blockIdx.x < a1Blk) {
    // alphas1: 8 lanes per node, 8 nodes per wave
    int w = (blockIdx.x * 256 + threadIdx.x) >> 6;
    int lane = threadIdx.x & 63;
    int n = w * 8 + (lane >> 3);
    int j = lane & 7;
    float4 xv = make_float4(0.f, 0.f, 0.f, 0.f);
    if (n < N_NODES) xv = *(const float4*)(x + (size_t)n * IN_DIM + j * 4);
    float ps[4] = {0.f, 0.f, 0.f, 0.f}, pd[4] = {0.f, 0.f, 0.f, 0.f};
    #pragma unroll
    for (int kk = 0; kk < 4; ++kk) {
      float xk = ((const float*)&xv)[kk];
      float4 ws = *(const float4*)(wa_s + (j * 4 + kk) * 4);
      float4 wd = *(const float4*)(wa_d + (j * 4 + kk) * 4);
      ps[0] += xk * ws.x; ps[1] += xk * ws.y; ps[2] += xk * ws.z; ps[3] += xk * ws.w;
      pd[0] += xk * wd.x; pd[1] += xk * wd.y; pd[2] += xk * wd.z; pd[3] += xk * wd.w;
    }
    #pragma unroll
    for (int off = 1; off < 8; off <<= 1) {
      #pragma unroll
      for (int h = 0; h < 4; ++h) {
        ps[h] += __shfl_xor(ps[h], off);
        pd[h] += __shfl_xor(pd[h], off);
      }
    }
    if (j == 0 && n < N_NODES) {
      *(float4*)(alps + n * 4) = make_float4(ps[0], ps[1], ps[2], ps[3]);
      *(float4*)(alpd + n * 4) = make_float4(pd[0], pd[1], pd[2], pd[3]);
    }
  } else {
    int e = (blockIdx.x - a1Blk) * 256 + threadIdx.x;
    if (e >= E_TOT) return;
    int s, d; edge_sd(ei, e, s, d);
    csr[rowptr[d] + rank[e]] = s;
  }
}

// x-space gather: half-wave per node; lane l owns head q=l>>3, channels kk=(l&7)*4.
// No online max (bounded logits). 8-edge batches.
__global__ __launch_bounds__(256) void gat_gather1_k(
    const int* __restrict__ rowptr, const int* __restrict__ csr,
    const float* __restrict__ alps, const float* __restrict__ alpd,
    const float* __restrict__ x, float* __restrict__ agg) {
  int wid2 = (blockIdx.x * 256 + threadIdx.x) >> 6;
  int lane = threadIdx.x & 63;
  int half = lane >> 5, l = lane & 31;
  int n = wid2 * 2 + half;
  bool valid = n < N_NODES;
  int q = l >> 3;                       // my head
  int kk = (l & 7) * 4;                 // my x-channel base
  int beg = valid ? rowptr[n] : 0;
  int end = valid ? rowptr[n + 1] : 0;
  float ad = valid ? alpd[n * HEADS + q] : 0.f;

  float den = 0.f;
  float4 acc = make_float4(0.f, 0.f, 0.f, 0.f);

  for (int i = beg; i < end; i += 8) {
    int s[8]; bool ok[8]; float xl[8]; float4 xv[8];
    #pragma unroll
    for (int j = 0; j < 8; ++j) { ok[j] = (i + j) < end; s[j] = ok[j] ? csr[i + j] : 0; }
    #pragma unroll
    for (int j = 0; j < 8; ++j) xl[j] = alps[s[j] * HEADS + q];
    #pragma unroll
    for (int j = 0; j < 8; ++j) xv[j] = *(const float4*)(x + (size_t)s[j] * IN_DIM + kk);
    float e[8];
    #pragma unroll
    for (int j = 0; j < 8; ++j) {
      float t = xl[j] + ad;
      t = fmaxf(t, NEG_SLOPE * t);
      e[j] = ok[j] ? ex2(t) : 0.f;
    }
    den += (((e[0] + e[1]) + (e[2] + e[3])) + ((e[4] + e[5]) + (e[6] + e[7])));
    #pragma unroll
    for (int j = 0; j < 8; ++j) {
      acc.x = fmaf(e[j], xv[j].x, acc.x);
      acc.y = fmaf(e[j], xv[j].y, acc.y);
      acc.z = fmaf(e[j], xv[j].z, acc.z);
      acc.w = fmaf(e[j], xv[j].w, acc.w);
    }
  }
  if (valid) {
    float inv = 1.f / (den + 1e-16f);
    float4 o = make_float4(acc.x * inv, acc.y * inv, acc.z * inv, acc.w * inv);
    *(float4*)(agg + (size_t)n * 128 + l * 4) = o;   // == [n][q*32 + kk]
  }
}

// out1 = relu(agg @ W1_head + b1), emitted as fp16 for the MFMA gemm
__global__ __launch_bounds__(256) void gemm_head1(const float* __restrict__ agg,
                                                  const float* __restrict__ W,
                                                  const float* __restrict__ b,
                                                  _Float16* __restrict__ A16) {
  __shared__ float As[32][68];
  __shared__ float Bs[32][64];
  const int row0 = blockIdx.x * 64;
  const int q = blockIdx.y;
  const int col0 = q * 64;
  const int t = threadIdx.x, tx = t & 15, ty = t >> 4;
  #pragma unroll
  for (int i = 0; i < 2; ++i) {
    int idx = t + i * 256;
    int r = idx >> 3, k4 = idx & 7;
    int rr = row0 + r;
    float4 a = make_float4(0.f, 0.f, 0.f, 0.f);
    if (rr < N_NODES) a = *(const float4*)(agg + (size_t)rr * 128 + q * 32 + k4 * 4);
    As[k4 * 4 + 0][r] = a.x;
    As[k4 * 4 + 1][r] = a.y;
    As[k4 * 4 + 2][r] = a.z;
    As[k4 * 4 + 3][r] = a.w;
  }
  #pragma unroll
  for (int i = 0; i < 2; ++i) {
    int idx = t + i * 256;
    int k = idx >> 4, c4 = idx & 15;
    *(float4*)&Bs[k][c4 * 4] = *(const float4*)(W + (size_t)k * D + col0 + c4 * 4);
  }
  __syncthreads();
  float acc[4][4] = {{0.f}};
  #pragma unroll
  for (int k = 0; k < 32; ++k) {
    float4 av = *(const float4*)&As[k][ty * 4];
    float4 bv = *(const float4*)&Bs[k][tx * 4];
    acc[0][0] += av.x * bv.x; acc[0][1] += av.x * bv.y;
    acc[0][2] += av.x * bv.z; acc[0][3] += av.x * bv.w;
    acc[1][0] += av.y * bv.x; acc[1][1] += av.y * bv.y;
    acc[1][2] += av.y * bv.z; acc[1][3] += av.y * bv.w;
    acc[2][0] += av.z * bv.x; acc[2][1] += av.z * bv.y;
    acc[2][2] += av.z * bv.z; acc[2][3] += av.z * bv.w;
    acc[3][0] += av.w * bv.x; acc[3][1] += av.w * bv.y;
    acc[3][2] += av.w * bv.z; acc[3][3] += av.w * bv.w;
  }
  float4 bv = *(const float4*)(b + col0 + tx * 4);
  const float bb[4] = {bv.x, bv.y, bv.z, bv.w};
  #pragma unroll
  for (int i = 0; i < 4; ++i) {
    int rr = row0 + ty * 4 + i;
    if (rr < N_NODES) {
      h16x4 o4;
      #pragma unroll
      for (int j = 0; j < 4; ++j)
        o4[j] = (_Float16)fmaxf(acc[i][j] + bb[j], 0.f);
      *(h16x4*)(A16 + (size_t)rr * D + col0 + tx * 4) = o4;
    }
  }
}

// ===== layer-2 GEMM via fp16 MFMA (single product); h2 out fp16, logits fp32 =====
__global__ __launch_bounds__(256) void gemm2_mfma(
    const _Float16* __restrict__ A16, const _Float16* __restrict__ Wt,
    const float* __restrict__ asrc, const float* __restrict__ adst,
    _Float16* __restrict__ h2, float* __restrict__ alps, float* __restrict__ alpd) {
  __shared__ __attribute__((aligned(16))) _Float16 As[128][40];
  __shared__ __attribute__((aligned(16))) _Float16 Bs[128][40];
  const int row0 = blockIdx.x * 128;
  const int col0 = blockIdx.y * 128;
  const int t = threadIdx.x;
  const int wave = t >> 6, lane = t & 63;
  const int wr = wave >> 1, wc = wave & 1;
  const int lg = lane >> 4, li = lane & 15;

  f32x4 acc[4][4];
  #pragma unroll
  for (int m = 0; m < 4; ++m)
    #pragma unroll
    for (int n = 0; n < 4; ++n) acc[m][n] = (f32x4)0.f;

  for (int kc = 0; kc < D; kc += 32) {
    #pragma unroll
    for (int i = 0; i < 2; ++i) {
      int idx = t + i * 256;          // 0..511
      int r = idx >> 2, seg = idx & 3;
      int rr = row0 + r;
      uint4 va = make_uint4(0, 0, 0, 0);
      if (rr < N_NODES) va = *(const uint4*)(A16 + (size_t)rr * D + kc + seg * 8);
      *(uint4*)&As[r][seg * 8] = va;
      uint4 vb = *(const uint4*)(Wt + (size_t)(col0 + r) * D + kc + seg * 8);
      *(uint4*)&Bs[r][seg * 8] = vb;
    }
    __syncthreads();
    h16x8 af[4], bf[4];
    #pragma unroll
    for (int m = 0; m < 4; ++m)
      af[m] = *(const h16x8*)&As[wr * 64 + m * 16 + li][lg * 8];
    #pragma unroll
    for (int n = 0; n < 4; ++n)
      bf[n] = *(const h16x8*)&Bs[wc * 64 + n * 16 + li][lg * 8];
    #pragma unroll
    for (int m = 0; m < 4; ++m)
      #pragma unroll
      for (int n = 0; n < 4; ++n)
        acc[m][n] = __builtin_amdgcn_mfma_f32_16x16x32_f16(af[m], bf[n], acc[m][n], 0, 0, 0);
    __syncthreads();
  }

  // store h2 tile as fp16
  #pragma unroll
  for (int m = 0; m < 4; ++m) {
    #pragma unroll
    for (int reg = 0; reg < 4; ++reg) {
      int rr = row0 + wr * 64 + m * 16 + lg * 4 + reg;
      if (rr < N_NODES) {
        #pragma unroll
        for (int n = 0; n < 4; ++n)
          h2[(size_t)rr * D + col0 + wc * 64 + n * 16 + li] = (_Float16)acc[m][n][reg];
      }
    }
  }

  // fused attention logits (fp32 accumulators): this wave's 64 cols == head q
  const int q = blockIdx.y * 2 + wc;
  float wsv[4], wdv[4];
  #pragma unroll
  for (int n = 0; n < 4; ++n) {
    wsv[n] = asrc[q * HID + n * 16 + li];
    wdv[n] = adst[q * HID + n * 16 + li];
  }
  #pragma unroll
  for (int m = 0; m < 4; ++m) {
    #pragma unroll
    for (int reg = 0; reg < 4; ++reg) {
      float ps = acc[m][0][reg] * wsv[0] + acc[m][1][reg] * wsv[1]
               + acc[m][2][reg] * wsv[2] + acc[m][3][reg] * wsv[3];
      float pd = acc[m][0][reg] * wdv[0] + acc[m][1][reg] * wdv[1]
               + acc[m][2][reg] * wdv[2] + acc[m][3][reg] * wdv[3];
      #pragma unroll
      for (int off = 1; off < 16; off <<= 1) {
        ps += __shfl_xor(ps, off);
        pd += __shfl_xor(pd, off);
      }
      int rr = row0 + wr * 64 + m * 16 + lg * 4 + reg;
      if (li == 0 && rr < N_NODES) {
        alps[rr * HEADS + q] = ps * LOG2E;
        alpd[rr * HEADS + q] = pd * LOG2E;
      }
    }
  }
}

// ====== layer-2 gather: 2 nodes/wave, 8 ch/lane, NO online max, 6-edge batch,
//        fused pair-head GEMV ======
__global__ __launch_bounds__(256) void gat_gather2_k(
    const int* __restrict__ rowptr, const int* __restrict__ csr,
    const float* __restrict__ alps, const float* __restrict__ alpd,
    const _Float16* __restrict__ h, const float* __restrict__ b,
    const float* __restrict__ hw,
    float* __restrict__ u, float* __restrict__ v) {
  int wid2 = (blockIdx.x * 256 + threadIdx.x) >> 6;
  int lane = threadIdx.x & 63;
  int half = lane >> 5, l = lane & 31;
  int n = wid2 * 2 + half;
  bool valid = n < N_NODES;
  int q = l >> 3;                      // head of my 8 channels
  int beg = valid ? rowptr[n] : 0;
  int end = valid ? rowptr[n + 1] : 0;
  float ad = valid ? alpd[n * HEADS + q] : 0.f;

  float den = 0.f;
  float acc[8] = {0.f, 0.f, 0.f, 0.f, 0.f, 0.f, 0.f, 0.f};

  for (int i = beg; i < end; i += 6) {
    int s[6]; bool ok[6]; float xl[6]; h16x8 hv[6];
    #pragma unroll
    for (int j = 0; j < 6; ++j) { ok[j] = (i + j) < end; s[j] = ok[j] ? csr[i + j] : 0; }
    #pragma unroll
    for (int j = 0; j < 6; ++j) xl[j] = alps[s[j] * HEADS + q];
    #pragma unroll
    for (int j = 0; j < 6; ++j) hv[j] = *(const h16x8*)(h + (size_t)s[j] * D + l * 8);
    float e[6];
    #pragma unroll
    for (int j = 0; j < 6; ++j) {
      float t = xl[j] + ad;
      t = fmaxf(t, NEG_SLOPE * t);
      e[j] = ok[j] ? ex2(t) : 0.f;
    }
    den += ((e[0] + e[1]) + (e[2] + e[3])) + (e[4] + e[5]);
    #pragma unroll
    for (int ch = 0; ch < 8; ++ch) {
      float a = acc[ch];
      a = fmaf((float)hv[0][ch], e[0], a);
      a = fmaf((float)hv[1][ch], e[1], a);
      a = fmaf((float)hv[2][ch], e[2], a);
      a = fmaf((float)hv[3][ch], e[3], a);
      a = fmaf((float)hv[4][ch], e[4], a);
      a = fmaf((float)hv[5][ch], e[5], a);
      acc[ch] = a;
    }
  }

  float inv = 1.f / (den + 1e-16f);
  float4 b0 = *(const float4*)(b + l * 8);
  float4 b1 = *(const float4*)(b + l * 8 + 4);
  float4 w00 = *(const float4*)(hw + l * 8);
  float4 w01 = *(const float4*)(hw + l * 8 + 4);
  float4 w10 = *(const float4*)(hw + D + l * 8);
  float4 w11 = *(const float4*)(hw + D + l * 8 + 4);
  const float* bb[2] = {(const float*)&b0, (const float*)&b1};
  const float* w0p[2] = {(const float*)&w00, (const float*)&w01};
  const float* w1p[2] = {(const float*)&w10, (const float*)&w11};
  float su = 0.f, sv = 0.f;
  #pragma unroll
  for (int ch = 0; ch < 8; ++ch) {
    float o = fmaxf(acc[ch] * inv + bb[ch >> 2][ch & 3], 0.f);
    su = fmaf(o, w0p[ch >> 2][ch & 3], su);
    sv = fmaf(o, w1p[ch >> 2][ch & 3], sv);
  }
  #pragma unroll
  for (int off = 16; off; off >>= 1) {    // xor masks <32 stay within the half
    su += __shfl_xor(su, off);
    sv += __shfl_xor(sv, off);
  }
  if (l == 0 && valid) { u[n] = su; v[n] = sv; }
}

// ---- pair lookup: out[p] = u[a] + v[b] + hb ----
__global__ void pair_lu_k(const int* __restrict__ pairs,
                          const float* __restrict__ u, const float* __restrict__ v,
                          const float* __restrict__ hb, float* __restrict__ out) {
  int g = blockIdx.x * 256 + threadIdx.x;
  if (g >= P_PAIRS) return;
  int a = pairs[g * 2], b = pairs[g * 2 + 1];
  out[g] = u[a] + v[b] + hb[0];
}

extern "C" void kernel_launch(void* const* d_in, const int* in_sizes, int n_in,
                              void* d_out, int out_size, void* d_ws, size_t ws_size,
                              hipStream_t stream) {
  const float* x    = (const float*)d_in[0];
  const int*   ei   = (const int*)d_in[1];
  const int*   prs  = (const int*)d_in[2];
  const float* W1   = (const float*)d_in[3];
  const float* as1  = (const float*)d_in[4];
  const float* ad1  = (const float*)d_in[5];
  const float* b1   = (const float*)d_in[6];
  const float* W2   = (const float*)d_in[7];
  const float* as2  = (const float*)d_in[8];
  const float* ad2  = (const float*)d_in[9];
  const float* b2   = (const float*)d_in[10];
  const float* hw   = (const float*)d_in[11];
  const float* hb   = (const float*)d_in[12];
  float* out = (float*)d_out;

  const int NPAD = 50048;   // 391*128

  char* w = (char*)d_ws;
  float* buf0 = (float*)w;             w += (size_t)N_NODES * D * 4;     // agg1 [n][128] / h2 fp16 [n][256]
  float* alps = (float*)w;             w += (size_t)N_NODES * HEADS * 4;
  float* alpd = (float*)w;             w += (size_t)N_NODES * HEADS * 4;
  int* rowptr = (int*)w;               w += (size_t)(N_NODES + 1) * 4;
  int* csr    = (int*)w;               w += (size_t)E_TOT * 4;
  float* uu   = (float*)w;             w += (size_t)N_NODES * 4;
  float* vv   = (float*)w;             w += (size_t)N_NODES * 4;
  float* wa_s = (float*)w;             w += 128 * 4;
  float* wa_d = (float*)w;             w += 128 * 4;
  _Float16* A16 = (_Float16*)w;        w += (size_t)NPAD * D * 2;        // out1 fp16
  _Float16* Wt  = (_Float16*)w;        w += (size_t)D * D * 2;           // W2T fp16

  _Float16* h2f16 = (_Float16*)buf0;

  // CSR-build temporaries aliased into buf0 (first real write to buf0 is
  // gat_gather1_k, which runs strictly after scatter_alphas_k on this stream)
  int* deg      = (int*)buf0;                 // N
  int* scan_out = deg + N_NODES;              // N
  int* bsum     = scan_out + N_NODES;         // 64
  int* rank     = bsum + 64;                  // E_TOT (fits: buf0 is 12.8M ints)

  const int eBlk     = (E_TOT + 255) / 256;               // 3321
  const int nScanBlk = (N_NODES + SCAN_BS - 1) / SCAN_BS; // 49
  const int nBlk256  = (N_NODES + 255) / 256;             // 196
  const int a1Blk    = (N_NODES * 8 + 255) / 256;         // 1563
  const int g1Blk    = ((N_NODES + 1) / 2 * 64 + 255) / 256; // 6250 (2 nodes/wave)
  const int pairBlk  = (P_PAIRS + 255) / 256;             // 782
  const dim3 headGrid((N_NODES + 63) / 64, HEADS);        // 782 x 4 (K=32 GEMM)
  const dim3 mfmaGrid(NPAD / 128, D / 128);               // 391 x 2

  // ---------- CSR build + weight prep (fused launches) ----------
  hipMemsetAsync(deg, 0, (size_t)N_NODES * 4, stream);
  count_prep_k<<<256 + eBlk, 256, 0, stream>>>(ei, deg, rank,
                                               W1, as1, ad1, W2, wa_s, wa_d, Wt);
  scan_block_k<<<nScanBlk, SCAN_BS, 0, stream>>>(deg, scan_out, bsum, N_NODES);
  add_off_k<<<nBlk256, 256, 0, stream>>>(scan_out, bsum, rowptr);
  scatter_alphas_k<<<a1Blk + eBlk, 256, 0, stream>>>(ei, rowptr, rank, csr,
                                                     x, wa_s, wa_d, alps, alpd, a1Blk);

  // ---------- layer 1 (x-space aggregation) ----------
  gat_gather1_k<<<g1Blk, 256, 0, stream>>>(rowptr, csr, alps, alpd, x, buf0);
  gemm_head1<<<headGrid, 256, 0, stream>>>(buf0, W1, b1, A16);

  // ---------- layer 2 (fp16 MFMA GEMM + fp16 gather w/ fused pair head) ----------
  gemm2_mfma<<<mfmaGrid, 256, 0, stream>>>(A16, Wt, as2, ad2, h2f16, alps, alpd);
  gat_gather2_k<<<g1Blk, 256, 0, stream>>>(rowptr, csr, alps, alpd, h2f16, b2, hw, uu, vv);

  // ---------- pair head ----------
  pair_lu_k<<<pairBlk, 256, 0, stream>>>(prs, uu, vv, hb, out);
}

// Round 16
// 286.675 us; speedup vs baseline: 1.3671x; 1.0857x over previous
//
#include <hip/hip_runtime.h>

#define N_NODES 50000
#define E_EDGES 800000
#define E_TOT   (E_EDGES + N_NODES)   // edges + self loops
#define P_PAIRS 200000
#define IN_DIM  32
#define HID     64
#define HEADS   4
#define D       256
#define NEG_SLOPE 0.2f
#define SCAN_BS 1024
#define LOG2E 1.4426950408889634f

typedef float    f32x4 __attribute__((ext_vector_type(4)));
typedef _Float16 h16x8 __attribute__((ext_vector_type(8)));
typedef _Float16 h16x4 __attribute__((ext_vector_type(4)));

__device__ __forceinline__ float ex2(float v) { return __builtin_amdgcn_exp2f(v); }

__device__ __forceinline__ void edge_sd(const int* __restrict__ ei, int e, int& s, int& d) {
  if (e < E_EDGES) { s = ei[e]; d = ei[E_EDGES + e]; }
  else             { s = d = e - E_EDGES; }
}

// ==== fused: W2T prep (blocks 0..255, +wa1 on block 0), W1T prep (256..287),
//             edge count (rest) ====
__global__ void count_prep_k(const int* __restrict__ ei, int* __restrict__ deg,
                             int* __restrict__ rank,
                             const float* __restrict__ W1,
                             const float* __restrict__ as1,
                             const float* __restrict__ ad1,
                             const float* __restrict__ W2,
                             float* __restrict__ wa_s, float* __restrict__ wa_d,
                             _Float16* __restrict__ Wt, _Float16* __restrict__ Wt1) {
  if (blockIdx.x < 256) {
    int g = blockIdx.x * 256 + threadIdx.x;   // 65536
    int col = g >> 8, k = g & 255;
    Wt[g] = (_Float16)W2[(size_t)k * D + col];
    if (blockIdx.x == 0) {
      int t = threadIdx.x;
      int kk = (t >> 2) & 31, h = t & 3;
      const float* att = (t < 128) ? as1 : ad1;
      float sum = 0.f;
      for (int c = 0; c < HID; ++c) sum += W1[kk * D + h * HID + c] * att[h * HID + c];
      float* dst = (t < 128) ? wa_s : wa_d;
      dst[kk * 4 + h] = sum * LOG2E;
    }
  } else if (blockIdx.x < 288) {
    int g = (blockIdx.x - 256) * 256 + threadIdx.x;   // 0..8191
    int col = g >> 5, k = g & 31;
    Wt1[g] = (_Float16)W1[(size_t)k * D + col];       // Wt1[col][k]
  } else {
    int e = (blockIdx.x - 288) * 256 + threadIdx.x;
    if (e >= E_TOT) return;
    int s, d; edge_sd(ei, e, s, d);
    rank[e] = atomicAdd(&deg[d], 1);
  }
}

__global__ __launch_bounds__(SCAN_BS) void scan_block_k(const int* __restrict__ in,
                                                        int* __restrict__ out,
                                                        int* __restrict__ bsum, int n) {
  __shared__ int tmp[SCAN_BS];
  int g = blockIdx.x * SCAN_BS + threadIdx.x;
  tmp[threadIdx.x] = (g < n) ? in[g] : 0;
  __syncthreads();
  for (int off = 1; off < SCAN_BS; off <<= 1) {
    int t = 0;
    if ((int)threadIdx.x >= off) t = tmp[threadIdx.x - off];
    __syncthreads();
    if ((int)threadIdx.x >= off) tmp[threadIdx.x] += t;
    __syncthreads();
  }
  if (g < n) out[g] = tmp[threadIdx.x];
  if (threadIdx.x == SCAN_BS - 1) bsum[blockIdx.x] = tmp[SCAN_BS - 1];
}

// add_off with inline top-scan over the (<=49) raw block sums
__global__ void add_off_k(const int* __restrict__ scan_out,
                          const int* __restrict__ bsum,
                          int* __restrict__ rowptr) {
  int g = blockIdx.x * 256 + threadIdx.x;
  if (g >= N_NODES) return;
  int blk = g / SCAN_BS;
  int add = 0;
  for (int b = 0; b < blk; ++b) add += bsum[b];
  rowptr[g + 1] = scan_out[g] + add;
  if (g == 0) rowptr[0] = 0;
}

// ===== fused: alphas1 (blocks 0..a1Blk) + rank-scatter (rest) =====
__global__ __launch_bounds__(256) void scatter_alphas_k(
    const int* __restrict__ ei, const int* __restrict__ rowptr,
    const int* __restrict__ rank, int* __restrict__ csr,
    const float* __restrict__ x,
    const float* __restrict__ wa_s, const float* __restrict__ wa_d,
    float* __restrict__ alps, float* __restrict__ alpd, int a1Blk) {
  if ((int)blockIdx.x < a1Blk) {
    int w = (blockIdx.x * 256 + threadIdx.x) >> 6;
    int lane = threadIdx.x & 63;
    int n = w * 8 + (lane >> 3);
    int j = lane & 7;
    float4 xv = make_float4(0.f, 0.f, 0.f, 0.f);
    if (n < N_NODES) xv = *(const float4*)(x + (size_t)n * IN_DIM + j * 4);
    float ps[4] = {0.f, 0.f, 0.f, 0.f}, pd[4] = {0.f, 0.f, 0.f, 0.f};
    #pragma unroll
    for (int kk = 0; kk < 4; ++kk) {
      float xk = ((const float*)&xv)[kk];
      float4 ws = *(const float4*)(wa_s + (j * 4 + kk) * 4);
      float4 wd = *(const float4*)(wa_d + (j * 4 + kk) * 4);
      ps[0] += xk * ws.x; ps[1] += xk * ws.y; ps[2] += xk * ws.z; ps[3] += xk * ws.w;
      pd[0] += xk * wd.x; pd[1] += xk * wd.y; pd[2] += xk * wd.z; pd[3] += xk * wd.w;
    }
    #pragma unroll
    for (int off = 1; off < 8; off <<= 1) {
      #pragma unroll
      for (int h = 0; h < 4; ++h) {
        ps[h] += __shfl_xor(ps[h], off);
        pd[h] += __shfl_xor(pd[h], off);
      }
    }
    if (j == 0 && n < N_NODES) {
      *(float4*)(alps + n * 4) = make_float4(ps[0], ps[1], ps[2], ps[3]);
      *(float4*)(alpd + n * 4) = make_float4(pd[0], pd[1], pd[2], pd[3]);
    }
  } else {
    int e = (blockIdx.x - a1Blk) * 256 + threadIdx.x;
    if (e >= E_TOT) return;
    int s, d; edge_sd(ei, e, s, d);
    csr[rowptr[d] + rank[e]] = s;
  }
}

// x-space gather -> fp16 agg: half-wave per node; lane l owns head q=l>>3,
// channels kk=(l&7)*4. No online max. 8-edge batches.
__global__ __launch_bounds__(256) void gat_gather1_k(
    const int* __restrict__ rowptr, const int* __restrict__ csr,
    const float* __restrict__ alps, const float* __restrict__ alpd,
    const float* __restrict__ x, _Float16* __restrict__ agg16) {
  int wid2 = (blockIdx.x * 256 + threadIdx.x) >> 6;
  int lane = threadIdx.x & 63;
  int half = lane >> 5, l = lane & 31;
  int n = wid2 * 2 + half;
  bool valid = n < N_NODES;
  int q = l >> 3;                       // my head
  int kk = (l & 7) * 4;                 // my x-channel base
  int beg = valid ? rowptr[n] : 0;
  int end = valid ? rowptr[n + 1] : 0;
  float ad = valid ? alpd[n * HEADS + q] : 0.f;

  float den = 0.f;
  float4 acc = make_float4(0.f, 0.f, 0.f, 0.f);

  for (int i = beg; i < end; i += 8) {
    int s[8]; bool ok[8]; float xl[8]; float4 xv[8];
    #pragma unroll
    for (int j = 0; j < 8; ++j) { ok[j] = (i + j) < end; s[j] = ok[j] ? csr[i + j] : 0; }
    #pragma unroll
    for (int j = 0; j < 8; ++j) xl[j] = alps[s[j] * HEADS + q];
    #pragma unroll
    for (int j = 0; j < 8; ++j) xv[j] = *(const float4*)(x + (size_t)s[j] * IN_DIM + kk);
    float e[8];
    #pragma unroll
    for (int j = 0; j < 8; ++j) {
      float t = xl[j] + ad;
      t = fmaxf(t, NEG_SLOPE * t);
      e[j] = ok[j] ? ex2(t) : 0.f;
    }
    den += (((e[0] + e[1]) + (e[2] + e[3])) + ((e[4] + e[5]) + (e[6] + e[7])));
    #pragma unroll
    for (int j = 0; j < 8; ++j) {
      acc.x = fmaf(e[j], xv[j].x, acc.x);
      acc.y = fmaf(e[j], xv[j].y, acc.y);
      acc.z = fmaf(e[j], xv[j].z, acc.z);
      acc.w = fmaf(e[j], xv[j].w, acc.w);
    }
  }
  if (valid) {
    float inv = 1.f / (den + 1e-16f);
    h16x4 o;
    o[0] = (_Float16)(acc.x * inv);
    o[1] = (_Float16)(acc.y * inv);
    o[2] = (_Float16)(acc.z * inv);
    o[3] = (_Float16)(acc.w * inv);
    *(h16x4*)(agg16 + (size_t)n * 128 + l * 4) = o;   // == [n][q*32 + kk]
  }
}

// out1 = relu(agg16 @ W1_head + b1) via fp16 MFMA, no LDS.
// grid (ceil(N/64), HEADS); 4 waves/block, wave = 16 rows x 64 cols (4 MFMAs, K=32).
__global__ __launch_bounds__(256) void gemm_head1_mfma(
    const _Float16* __restrict__ agg16, const _Float16* __restrict__ Wt1,
    const float* __restrict__ b, _Float16* __restrict__ A16) {
  const int t = threadIdx.x;
  const int wave = t >> 6, lane = t & 63;
  const int lg = lane >> 4, li = lane & 15;
  const int q = blockIdx.y;
  const int row0 = blockIdx.x * 64 + wave * 16;

  h16x8 af = {};
  int arow = row0 + li;
  if (arow < N_NODES)
    af = *(const h16x8*)(agg16 + (size_t)arow * 128 + q * 32 + lg * 8);

  h16x8 bf[4];
  #pragma unroll
  for (int n = 0; n < 4; ++n)
    bf[n] = *(const h16x8*)(Wt1 + (size_t)(q * 64 + n * 16 + li) * 32 + lg * 8);

  f32x4 acc[4];
  #pragma unroll
  for (int n = 0; n < 4; ++n)
    acc[n] = __builtin_amdgcn_mfma_f32_16x16x32_f16(af, bf[n], (f32x4)0.f, 0, 0, 0);

  #pragma unroll
  for (int n = 0; n < 4; ++n) {
    int col = q * 64 + n * 16 + li;
    float bb = b[col];
    #pragma unroll
    for (int reg = 0; reg < 4; ++reg) {
      int rr = row0 + lg * 4 + reg;
      if (rr < N_NODES)
        A16[(size_t)rr * D + col] = (_Float16)fmaxf(acc[n][reg] + bb, 0.f);
    }
  }
}

// ===== layer-2 GEMM via fp16 MFMA (single product); h2 out fp16, logits fp32 =====
__global__ __launch_bounds__(256) void gemm2_mfma(
    const _Float16* __restrict__ A16, const _Float16* __restrict__ Wt,
    const float* __restrict__ asrc, const float* __restrict__ adst,
    _Float16* __restrict__ h2, float* __restrict__ alps, float* __restrict__ alpd) {
  __shared__ __attribute__((aligned(16))) _Float16 As[128][40];
  __shared__ __attribute__((aligned(16))) _Float16 Bs[128][40];
  const int row0 = blockIdx.x * 128;
  const int col0 = blockIdx.y * 128;
  const int t = threadIdx.x;
  const int wave = t >> 6, lane = t & 63;
  const int wr = wave >> 1, wc = wave & 1;
  const int lg = lane >> 4, li = lane & 15;

  f32x4 acc[4][4];
  #pragma unroll
  for (int m = 0; m < 4; ++m)
    #pragma unroll
    for (int n = 0; n < 4; ++n) acc[m][n] = (f32x4)0.f;

  for (int kc = 0; kc < D; kc += 32) {
    #pragma unroll
    for (int i = 0; i < 2; ++i) {
      int idx = t + i * 256;          // 0..511
      int r = idx >> 2, seg = idx & 3;
      int rr = row0 + r;
      uint4 va = make_uint4(0, 0, 0, 0);
      if (rr < N_NODES) va = *(const uint4*)(A16 + (size_t)rr * D + kc + seg * 8);
      *(uint4*)&As[r][seg * 8] = va;
      uint4 vb = *(const uint4*)(Wt + (size_t)(col0 + r) * D + kc + seg * 8);
      *(uint4*)&Bs[r][seg * 8] = vb;
    }
    __syncthreads();
    h16x8 af[4], bf[4];
    #pragma unroll
    for (int m = 0; m < 4; ++m)
      af[m] = *(const h16x8*)&As[wr * 64 + m * 16 + li][lg * 8];
    #pragma unroll
    for (int n = 0; n < 4; ++n)
      bf[n] = *(const h16x8*)&Bs[wc * 64 + n * 16 + li][lg * 8];
    #pragma unroll
    for (int m = 0; m < 4; ++m)
      #pragma unroll
      for (int n = 0; n < 4; ++n)
        acc[m][n] = __builtin_amdgcn_mfma_f32_16x16x32_f16(af[m], bf[n], acc[m][n], 0, 0, 0);
    __syncthreads();
  }

  // store h2 tile as fp16
  #pragma unroll
  for (int m = 0; m < 4; ++m) {
    #pragma unroll
    for (int reg = 0; reg < 4; ++reg) {
      int rr = row0 + wr * 64 + m * 16 + lg * 4 + reg;
      if (rr < N_NODES) {
        #pragma unroll
        for (int n = 0; n < 4; ++n)
          h2[(size_t)rr * D + col0 + wc * 64 + n * 16 + li] = (_Float16)acc[m][n][reg];
      }
    }
  }

  // fused attention logits (fp32 accumulators): this wave's 64 cols == head q
  const int q = blockIdx.y * 2 + wc;
  float wsv[4], wdv[4];
  #pragma unroll
  for (int n = 0; n < 4; ++n) {
    wsv[n] = asrc[q * HID + n * 16 + li];
    wdv[n] = adst[q * HID + n * 16 + li];
  }
  #pragma unroll
  for (int m = 0; m < 4; ++m) {
    #pragma unroll
    for (int reg = 0; reg < 4; ++reg) {
      float ps = acc[m][0][reg] * wsv[0] + acc[m][1][reg] * wsv[1]
               + acc[m][2][reg] * wsv[2] + acc[m][3][reg] * wsv[3];
      float pd = acc[m][0][reg] * wdv[0] + acc[m][1][reg] * wdv[1]
               + acc[m][2][reg] * wdv[2] + acc[m][3][reg] * wdv[3];
      #pragma unroll
      for (int off = 1; off < 16; off <<= 1) {
        ps += __shfl_xor(ps, off);
        pd += __shfl_xor(pd, off);
      }
      int rr = row0 + wr * 64 + m * 16 + lg * 4 + reg;
      if (li == 0 && rr < N_NODES) {
        alps[rr * HEADS + q] = ps * LOG2E;
        alpd[rr * HEADS + q] = pd * LOG2E;
      }
    }
  }
}

// ====== layer-2 gather: 2 nodes/wave, 8 ch/lane, NO online max, 6-edge batch,
//        fused pair-head GEMV ======
__global__ __launch_bounds__(256) void gat_gather2_k(
    const int* __restrict__ rowptr, const int* __restrict__ csr,
    const float* __restrict__ alps, const float* __restrict__ alpd,
    const _Float16* __restrict__ h, const float* __restrict__ b,
    const float* __restrict__ hw,
    float* __restrict__ u, float* __restrict__ v) {
  int wid2 = (blockIdx.x * 256 + threadIdx.x) >> 6;
  int lane = threadIdx.x & 63;
  int half = lane >> 5, l = lane & 31;
  int n = wid2 * 2 + half;
  bool valid = n < N_NODES;
  int q = l >> 3;                      // head of my 8 channels
  int beg = valid ? rowptr[n] : 0;
  int end = valid ? rowptr[n + 1] : 0;
  float ad = valid ? alpd[n * HEADS + q] : 0.f;

  float den = 0.f;
  float acc[8] = {0.f, 0.f, 0.f, 0.f, 0.f, 0.f, 0.f, 0.f};

  for (int i = beg; i < end; i += 6) {
    int s[6]; bool ok[6]; float xl[6]; h16x8 hv[6];
    #pragma unroll
    for (int j = 0; j < 6; ++j) { ok[j] = (i + j) < end; s[j] = ok[j] ? csr[i + j] : 0; }
    #pragma unroll
    for (int j = 0; j < 6; ++j) xl[j] = alps[s[j] * HEADS + q];
    #pragma unroll
    for (int j = 0; j < 6; ++j) hv[j] = *(const h16x8*)(h + (size_t)s[j] * D + l * 8);
    float e[6];
    #pragma unroll
    for (int j = 0; j < 6; ++j) {
      float t = xl[j] + ad;
      t = fmaxf(t, NEG_SLOPE * t);
      e[j] = ok[j] ? ex2(t) : 0.f;
    }
    den += ((e[0] + e[1]) + (e[2] + e[3])) + (e[4] + e[5]);
    #pragma unroll
    for (int ch = 0; ch < 8; ++ch) {
      float a = acc[ch];
      a = fmaf((float)hv[0][ch], e[0], a);
      a = fmaf((float)hv[1][ch], e[1], a);
      a = fmaf((float)hv[2][ch], e[2], a);
      a = fmaf((float)hv[3][ch], e[3], a);
      a = fmaf((float)hv[4][ch], e[4], a);
      a = fmaf((float)hv[5][ch], e[5], a);
      acc[ch] = a;
    }
  }

  float inv = 1.f / (den + 1e-16f);
  float4 b0 = *(const float4*)(b + l * 8);
  float4 b1 = *(const float4*)(b + l * 8 + 4);
  float4 w00 = *(const float4*)(hw + l * 8);
  float4 w01 = *(const float4*)(hw + l * 8 + 4);
  float4 w10 = *(const float4*)(hw + D + l * 8);
  float4 w11 = *(const float4*)(hw + D + l * 8 + 4);
  const float* bb[2] = {(const float*)&b0, (const float*)&b1};
  const float* w0p[2] = {(const float*)&w00, (const float*)&w01};
  const float* w1p[2] = {(const float*)&w10, (const float*)&w11};
  float su = 0.f, sv = 0.f;
  #pragma unroll
  for (int ch = 0; ch < 8; ++ch) {
    float o = fmaxf(acc[ch] * inv + bb[ch >> 2][ch & 3], 0.f);
    su = fmaf(o, w0p[ch >> 2][ch & 3], su);
    sv = fmaf(o, w1p[ch >> 2][ch & 3], sv);
  }
  #pragma unroll
  for (int off = 16; off; off >>= 1) {    // xor masks <32 stay within the half
    su += __shfl_xor(su, off);
    sv += __shfl_xor(sv, off);
  }
  if (l == 0 && valid) { u[n] = su; v[n] = sv; }
}

// ---- pair lookup: out[p] = u[a] + v[b] + hb ----
__global__ void pair_lu_k(const int* __restrict__ pairs,
                          const float* __restrict__ u, const float* __restrict__ v,
                          const float* __restrict__ hb, float* __restrict__ out) {
  int g = blockIdx.x * 256 + threadIdx.x;
  if (g >= P_PAIRS) return;
  int a = pairs[g * 2], b = pairs[g * 2 + 1];
  out[g] = u[a] + v[b] + hb[0];
}

extern "C" void kernel_launch(void* const* d_in, const int* in_sizes, int n_in,
                              void* d_out, int out_size, void* d_ws, size_t ws_size,
                              hipStream_t stream) {
  const float* x    = (const float*)d_in[0];
  const int*   ei   = (const int*)d_in[1];
  const int*   prs  = (const int*)d_in[2];
  const float* W1   = (const float*)d_in[3];
  const float* as1  = (const float*)d_in[4];
  const float* ad1  = (const float*)d_in[5];
  const float* b1   = (const float*)d_in[6];
  const float* W2   = (const float*)d_in[7];
  const float* as2  = (const float*)d_in[8];
  const float* ad2  = (const float*)d_in[9];
  const float* b2   = (const float*)d_in[10];
  const float* hw   = (const float*)d_in[11];
  const float* hb   = (const float*)d_in[12];
  float* out = (float*)d_out;

  const int NPAD = 50048;   // 391*128

  char* w = (char*)d_ws;
  float* buf0 = (float*)w;             w += (size_t)N_NODES * D * 4;     // agg16 [n][128]f16 / h2 [n][256]f16
  float* alps = (float*)w;             w += (size_t)N_NODES * HEADS * 4;
  float* alpd = (float*)w;             w += (size_t)N_NODES * HEADS * 4;
  int* rowptr = (int*)w;               w += (size_t)(N_NODES + 1) * 4;
  int* csr    = (int*)w;               w += (size_t)E_TOT * 4;
  float* uu   = (float*)w;             w += (size_t)N_NODES * 4;
  float* vv   = (float*)w;             w += (size_t)N_NODES * 4;
  float* wa_s = (float*)w;             w += 128 * 4;
  float* wa_d = (float*)w;             w += 128 * 4;
  _Float16* A16 = (_Float16*)w;        w += (size_t)NPAD * D * 2;        // out1 fp16
  _Float16* Wt  = (_Float16*)w;        w += (size_t)D * D * 2;           // W2T fp16
  _Float16* Wt1 = (_Float16*)w;        w += (size_t)D * IN_DIM * 2;      // W1T fp16

  _Float16* agg16 = (_Float16*)buf0;   // [n][128] fp16, dead after gemm_head1
  _Float16* h2f16 = (_Float16*)buf0;   // [n][256] fp16, written by gemm2

  // CSR-build temporaries aliased into buf0 (first real write to buf0 is
  // gat_gather1_k, which runs strictly after scatter_alphas_k on this stream)
  int* deg      = (int*)buf0;                 // N
  int* scan_out = deg + N_NODES;              // N
  int* bsum     = scan_out + N_NODES;         // 64
  int* rank     = bsum + 64;                  // E_TOT (fits: buf0 is 12.8M ints)

  const int eBlk     = (E_TOT + 255) / 256;               // 3321
  const int nScanBlk = (N_NODES + SCAN_BS - 1) / SCAN_BS; // 49
  const int nBlk256  = (N_NODES + 255) / 256;             // 196
  const int a1Blk    = (N_NODES * 8 + 255) / 256;         // 1563
  const int g1Blk    = ((N_NODES + 1) / 2 * 64 + 255) / 256; // 6250 (2 nodes/wave)
  const int pairBlk  = (P_PAIRS + 255) / 256;             // 782
  const dim3 headGrid((N_NODES + 63) / 64, HEADS);        // 782 x 4
  const dim3 mfmaGrid(NPAD / 128, D / 128);               // 391 x 2

  // ---------- CSR build + weight prep (fused launches) ----------
  hipMemsetAsync(deg, 0, (size_t)N_NODES * 4, stream);
  count_prep_k<<<288 + eBlk, 256, 0, stream>>>(ei, deg, rank,
                                               W1, as1, ad1, W2, wa_s, wa_d, Wt, Wt1);
  scan_block_k<<<nScanBlk, SCAN_BS, 0, stream>>>(deg, scan_out, bsum, N_NODES);
  add_off_k<<<nBlk256, 256, 0, stream>>>(scan_out, bsum, rowptr);
  scatter_alphas_k<<<a1Blk + eBlk, 256, 0, stream>>>(ei, rowptr, rank, csr,
                                                     x, wa_s, wa_d, alps, alpd, a1Blk);

  // ---------- layer 1 (x-space aggregation, fp16 agg + MFMA head) ----------
  gat_gather1_k<<<g1Blk, 256, 0, stream>>>(rowptr, csr, alps, alpd, x, agg16);
  gemm_head1_mfma<<<headGrid, 256, 0, stream>>>(agg16, Wt1, b1, A16);

  // ---------- layer 2 (fp16 MFMA GEMM + fp16 gather w/ fused pair head) ----------
  gemm2_mfma<<<mfmaGrid, 256, 0, stream>>>(A16, Wt, as2, ad2, h2f16, alps, alpd);
  gat_gather2_k<<<g1Blk, 256, 0, stream>>>(rowptr, csr, alps, alpd, h2f16, b2, hw, uu, vv);

  // ---------- pair head ----------
  pair_lu_k<<<pairBlk, 256, 0, stream>>>(prs, uu, vv, hb, out);
}